// Round 11
// baseline (113.870 us; speedup 1.0000x reference)
//
#include <hip/hip_runtime.h>

typedef __attribute__((ext_vector_type(8))) short bf16x8;
typedef __attribute__((ext_vector_type(4))) float f32x4;

#define T_SEQ 1024
#define NH 16
#define CEMB 1024

__device__ __forceinline__ float asf(unsigned int u){ union{unsigned int i;float f;}x; x.i=u; return x.f; }
__device__ __forceinline__ float bf2f(unsigned short u){ return asf(((unsigned int)u)<<16); }
__device__ __forceinline__ unsigned short f2bf(float f){
  union{float f;unsigned int i;}x; x.f=f;
  unsigned int r = x.i + 0x7FFFu + ((x.i>>16)&1u);
  return (unsigned short)(r>>16);
}
__device__ __forceinline__ f32x4 MFMA16(bf16x8 a, bf16x8 b, f32x4 c){
  return __builtin_amdgcn_mfma_f32_16x16x32_bf16(a, b, c, 0,0,0);
}

// ---------------- fused cvt + gates (pass1: float4 cvt; pass2: r5-exact gates, L1-hot x) ----------------
__global__ __launch_bounds__(256)
void prep2_kernel(const float* __restrict__ x, const float* __restrict__ Wg,
                  const float* __restrict__ bg, unsigned short* __restrict__ x_bf,
                  float* __restrict__ gates){
  const int lane = threadIdx.x & 63;
  const int row  = blockIdx.x*4 + (threadIdx.x>>6);
  // pass 1: bf16 convert (vectorized, coalesced)
  const float4* xr4 = reinterpret_cast<const float4*>(x + (size_t)row*CEMB);
  ushort4* xbr = reinterpret_cast<ushort4*>(x_bf + (size_t)row*CEMB);
  #pragma unroll
  for (int i=0;i<4;i++){
    float4 v = xr4[i*64 + lane];
    ushort4 o; o.x=f2bf(v.x); o.y=f2bf(v.y); o.z=f2bf(v.z); o.w=f2bf(v.w);
    xbr[i*64 + lane] = o;
  }
  // pass 2: gates (scalar x re-read now cache-hot; Wg reads coalesced as in r5)
  const float* xr = x + (size_t)row*CEMB;
  float acc[NH];
  #pragma unroll
  for (int h=0;h<NH;h++) acc[h]=0.f;
  for (int i=0;i<CEMB/64;i++){
    float xv = xr[i*64 + lane];
    const float4* wg = reinterpret_cast<const float4*>(Wg + (size_t)(i*64+lane)*NH);
    float4 a=wg[0], b=wg[1], c=wg[2], d=wg[3];
    acc[0]+=xv*a.x; acc[1]+=xv*a.y; acc[2]+=xv*a.z; acc[3]+=xv*a.w;
    acc[4]+=xv*b.x; acc[5]+=xv*b.y; acc[6]+=xv*b.z; acc[7]+=xv*b.w;
    acc[8]+=xv*c.x; acc[9]+=xv*c.y; acc[10]+=xv*c.z; acc[11]+=xv*c.w;
    acc[12]+=xv*d.x; acc[13]+=xv*d.y; acc[14]+=xv*d.z; acc[15]+=xv*d.w;
  }
  #pragma unroll
  for (int h=0;h<NH;h++){
    #pragma unroll
    for (int m=32;m;m>>=1) acc[h] += __shfl_xor(acc[h], m, 64);
  }
  float mx = -1e30f;
  #pragma unroll
  for (int h=0;h<NH;h++){ acc[h] += bg[h]; mx = fmaxf(mx, acc[h]); }
  float s = 0.f;
  #pragma unroll
  for (int h=0;h<NH;h++){ acc[h] = __expf(acc[h]-mx); s += acc[h]; }
  float g = 0.f;
  #pragma unroll
  for (int h=0;h<NH;h++) g = (lane==h) ? acc[h]/s : g;
  if (lane < NH) gates[(size_t)row*NH + lane] = g;
}

// ---------------- both weight transposes, one launch (blockIdx-partitioned) ----------------
__global__ void wtrans_kernel(const float* __restrict__ Wqk, unsigned short* __restrict__ WqkT,
                              const float* __restrict__ Wproj, unsigned short* __restrict__ WprojT){
  __shared__ float tile[32][33];
  int blk = blockIdx.x;
  const float* W; unsigned short* Wt; int R, C, bx, by;
  if (blk < 2048){ W = Wqk;   Wt = WqkT;   R = 1024; C = 2048; bx = blk & 63; by = blk >> 6; }
  else { blk -= 2048; W = Wproj; Wt = WprojT; R = 1024; C = 1024; bx = blk & 31; by = blk >> 5; }
  const int c0 = bx*32, r0 = by*32;
  const int tx = threadIdx.x, ty = threadIdx.y;   // (32,8)
  #pragma unroll
  for (int i=0;i<32;i+=8) tile[ty+i][tx] = W[(size_t)(r0+ty+i)*C + c0 + tx];
  __syncthreads();
  #pragma unroll
  for (int i=0;i<32;i+=8) Wt[(size_t)(c0+ty+i)*R + r0 + tx] = f2bf(tile[tx][ty+i]);
}

// ---------------- bf16 MFMA GEMM: C[M][N] = A[M][K] @ Bt[N][K]^T + bias ----------------
// Double-buffered stage-ahead (2-phase). BM template: 128 (waves 2x2, 64x64 each)
// or 64 (waves 1x4, 64x32 each; 48KB LDS -> 3 blocks/CU).
template<bool OUT_BF16, int BM>
__global__ __launch_bounds__(256)
void gemm_bt_kernel(const unsigned short* __restrict__ A, const unsigned short* __restrict__ Bt,
                    const float* __restrict__ bias, void* __restrict__ Cptr,
                    int M, int N, int K){
  constexpr int WCN   = (BM==128) ? 2 : 4;       // wave cols
  constexpr int MFRAG = 4;                        // 16-row frags per wave
  constexpr int NFRAG = 4/(WCN/2);               // 128/WCN/16
  constexpr int WCW   = 128/WCN;                 // wave col width
  constexpr int AISS  = BM/32;                   // A stage issues
  __shared__ unsigned short lA0[BM*64], lA1[BM*64];
  __shared__ unsigned short lB0[128*64], lB1[128*64];
  const int tid = threadIdx.x;
  const int wid = tid>>6, lane = tid&63;
  const int nbm = M/BM;
  const int bid = blockIdx.x;
  const int bm = bid % nbm, bn = bid / nbm;
  const int wr = (BM==128) ? (wid>>1) : 0;
  const int wc = (BM==128) ? (wid&1) : wid;
  f32x4 acc[MFRAG][NFRAG] = {};

  const unsigned short* gA = A + (size_t)bm*BM*K;
  const unsigned short* gB = Bt + (size_t)bn*128*K;
  const int srow = lane>>3;
  const int schunk = lane&7;

#define GSTAGE(LA, LB, KK) do { \
  _Pragma("unroll") \
  for (int i_=0;i_<AISS;i_++){ \
    int rowi_ = (wid*AISS+i_)*8 + srow; \
    int cc_ = schunk ^ (rowi_ & 7); \
    __builtin_amdgcn_global_load_lds((const __attribute__((address_space(1))) void*)(gA + (size_t)rowi_*K + (KK) + cc_*8), \
        (__attribute__((address_space(3))) void*)&LA[(wid*AISS+i_)*512], 16, 0, 0); \
  } \
  _Pragma("unroll") \
  for (int i_=0;i_<4;i_++){ \
    int rowi_ = (wid*4+i_)*8 + srow; \
    int cc_ = schunk ^ (rowi_ & 7); \
    __builtin_amdgcn_global_load_lds((const __attribute__((address_space(1))) void*)(gB + (size_t)rowi_*K + (KK) + cc_*8), \
        (__attribute__((address_space(3))) void*)&LB[(wid*4+i_)*512], 16, 0, 0); \
  } \
} while(0)

#define GCOMPUTE(LA, LB) do { \
  _Pragma("unroll") \
  for (int ks_=0; ks_<2; ks_++){ \
    bf16x8 af_[MFRAG], bf_[NFRAG]; \
    _Pragma("unroll") \
    for (int m_=0;m_<MFRAG;m_++){ \
      int r_ = wr*64 + m_*16 + (lane&15); \
      int p_ = (ks_*4 + (lane>>4)) ^ (r_&7); \
      af_[m_] = *reinterpret_cast<const bf16x8*>(&LA[r_*64 + p_*8]); \
    } \
    _Pragma("unroll") \
    for (int n_=0;n_<NFRAG;n_++){ \
      int r_ = wc*WCW + n_*16 + (lane&15); \
      int p_ = (ks_*4 + (lane>>4)) ^ (r_&7); \
      bf_[n_] = *reinterpret_cast<const bf16x8*>(&LB[r_*64 + p_*8]); \
    } \
    _Pragma("unroll") \
    for (int m_=0;m_<MFRAG;m_++) \
      _Pragma("unroll") \
      for (int n_=0;n_<NFRAG;n_++) \
        acc[m_][n_] = __builtin_amdgcn_mfma_f32_16x16x32_bf16(af_[m_], bf_[n_], acc[m_][n_], 0,0,0); \
  } \
} while(0)

  GSTAGE(lA0, lB0, 0);
  __syncthreads();
  for (int k0=0; k0<K; k0+=128){
    GSTAGE(lA1, lB1, k0+64);     // issue next-half loads, no wait
    GCOMPUTE(lA0, lB0);          // MFMA on current (hides stage latency)
    __syncthreads();             // drain (after compute) + publish lA1/lB1
    if (k0+128 < K) GSTAGE(lA0, lB0, k0+128);
    GCOMPUTE(lA1, lB1);
    __syncthreads();
  }
#undef GSTAGE
#undef GCOMPUTE

  const int rq = lane>>4;
  const int cl = lane&15;
  #pragma unroll
  for (int n=0;n<NFRAG;n++){
    int col = bn*128 + wc*WCW + n*16 + cl;
    float bv = bias[col];
    #pragma unroll
    for (int m=0;m<MFRAG;m++){
      int row = bm*BM + wr*64 + m*16 + rq*4;
      #pragma unroll
      for (int r=0;r<4;r++){
        float v = acc[m][n][r] + bv;
        if (OUT_BF16) ((unsigned short*)Cptr)[(size_t)(row+r)*N + col] = f2bf(v);
        else          ((float*)Cptr)[(size_t)(row+r)*N + col] = v;
      }
    }
  }
}

// ---------------- fragment pack: K rows -> Kpack (QK B-frags) + Vpack (PV B-frags) ----------------
__global__ __launch_bounds__(256)
void kpack_kernel(const unsigned short* __restrict__ qk,
                  unsigned short* __restrict__ Kpack, unsigned short* __restrict__ Vpack){
  __shared__ unsigned short lT[64][68];
  const int blk = blockIdx.x;          // 1024 = 64 bh * 16 tgroups
  const int t0 = (blk & 15) * 64;
  const int bh = blk >> 4;
  const int b = bh >> 4, h = bh & 15;
  const int tid = threadIdx.x;
  #pragma unroll
  for (int it=0; it<2; it++){
    int idx = tid + it*256;
    int row = idx >> 3, c = idx & 7;
    uint4 v = *reinterpret_cast<const uint4*>(qk + ((size_t)(b*T_SEQ + t0 + row)*2048 + 1024 + h*64 + c*8));
    *reinterpret_cast<uint4*>(&lT[row][c*8]) = v;
  }
  __syncthreads();
  const int wid = tid>>6, lane = tid&63;
  const int g = lane>>4, li = lane&15;
  const int tile = wid>>1;             // 0..1 (32-row tile within the 64 staged rows)
  const int kt = (t0>>5) + tile;
  #pragma unroll
  for (int ff=0; ff<2; ff++){
    const int f = (wid&1)*2 + ff;
    const int row = tile*32 + ((f>>1)<<4) + li;
    const int col = (f&1)*32 + g*8;
    uint4 v = *reinterpret_cast<const uint4*>(&lT[row][col]);
    *reinterpret_cast<uint4*>(Kpack + ((((size_t)bh*32 + kt)*4 + f)*64 + lane)*8) = v;
  }
  #pragma unroll
  for (int ff=0; ff<2; ff++){
    const int d4 = (wid&1)*2 + ff;
    unsigned short vv[8];
    #pragma unroll
    for (int j=0;j<8;j++) vv[j] = lT[tile*32 + g*8 + j][d4*16 + li];
    *reinterpret_cast<uint4*>(Vpack + ((((size_t)bh*32 + kt)*4 + d4)*64 + lane)*8) = *reinterpret_cast<const uint4*>(vv);
  }
}

// ---------------- split-K MFMA attention, no-max softmax, packed coalesced frags ----------------
__global__ __launch_bounds__(256)
void attn_mfma_kernel(const unsigned short* __restrict__ qk,
                      const unsigned short* __restrict__ Kpack,
                      const unsigned short* __restrict__ Vpack,
                      const float* __restrict__ gates, unsigned short* __restrict__ gated,
                      unsigned short* __restrict__ pO, float* __restrict__ pL){
  __shared__ unsigned short lP[4][16*40];
  const int tid = threadIdx.x;
  const int wid = tid>>6, lane = tid&63;
  const int g = lane>>4, li = lane&15;

  const int W = blockIdx.x*4 + wid;
  int h, c, b, qw16; bool partial;
  if (W < 1024){ h = 0; c = W>>8; int r = W&255; b = r>>6; qw16 = r&63; partial = true; }
  else if (W < 1536){ h = 1; int Wp = W-1024; c = Wp>>8; int r = Wp&255; b = r>>6; qw16 = r&63; partial = true; }
  else { int Wp = W-1536; h = 2 + (Wp>>8); int r = Wp&255; b = r>>6; qw16 = r&63; c = 0; partial = false; }

  int w = 1024 >> h; if (w < 4) w = 4;
  const int qw0 = qw16*16;
  const int bh = b*NH + h;

  int mylo = qw0 - w + 1; if (mylo < 0) mylo = 0;
  const int kt_lo_full = mylo >> 5;
  const int kt_hi_full = (qw0 + 15) >> 5;
  const int slot = (b*64 + qw16)*6 + ((h==0) ? c : 4 + c);

  int kt_start, kt_end;
  if (partial){
    const int CH = (h==0) ? 8 : 9;
    kt_end = kt_hi_full - c*CH;
    kt_start = kt_end - (CH-1); if (kt_start < kt_lo_full) kt_start = kt_lo_full;
    if (kt_end < kt_lo_full){
      unsigned short* po = pO + (size_t)slot*16*64;
      #pragma unroll
      for (int r2=0;r2<4;r2++){
        const int row = g*4 + r2;
        #pragma unroll
        for (int d4=0; d4<4; d4++) po[row*64 + d4*16 + li] = 0;
      }
      if (li == 0){
        #pragma unroll
        for (int r2=0;r2<4;r2++) pL[(size_t)slot*16 + g*4 + r2] = 0.f;
      }
      return;
    }
  } else {
    kt_start = kt_lo_full; kt_end = kt_hi_full;
  }

  // Q A-fragments (once per wave)
  const unsigned short* qbase = qk + ((size_t)(b*T_SEQ + qw0 + li)*2048 + h*64 + g*8);
  const bf16x8 aq0 = *reinterpret_cast<const bf16x8*>(qbase);
  const bf16x8 aq1 = *reinterpret_cast<const bf16x8*>(qbase + 32);

  f32x4 oacc[4] = {};
  float lsum[4] = {0.f,0.f,0.f,0.f};

  const unsigned short* kp = Kpack + (size_t)bh*32*4*512;
  const unsigned short* vp = Vpack + (size_t)bh*32*4*512;
  const int loff = lane*8;

  bf16x8 kf[4], kn[4], bv[4];
  #pragma unroll
  for (int f=0; f<4; f++)
    kf[f] = *reinterpret_cast<const bf16x8*>(kp + (kt_start*4 + f)*512 + loff);

  for (int kt = kt_start; kt <= kt_end; ++kt){
    // V frags (current tile), coalesced; issued early, consumed after exp
    #pragma unroll
    for (int d4=0; d4<4; d4++)
      bv[d4] = *reinterpret_cast<const bf16x8*>(vp + (kt*4 + d4)*512 + loff);
    // prefetch next K frags (clamped, branch-free)
    {
      const int ktn = (kt < kt_end) ? kt+1 : kt_end;
      #pragma unroll
      for (int f=0; f<4; f++)
        kn[f] = *reinterpret_cast<const bf16x8*>(kp + (ktn*4 + f)*512 + loff);
    }

    // ---- QK^T ----
    f32x4 s0 = {}, s1 = {};
    s0 = MFMA16(aq0, kf[0], s0);
    s0 = MFMA16(aq1, kf[1], s0);
    s1 = MFMA16(aq0, kf[2], s1);
    s1 = MFMA16(aq1, kf[3], s1);

    // ---- no-max softmax accumulate: p = valid ? exp(s/8) : 0 ----
    const int k0 = kt*32;
    #pragma unroll
    for (int r=0;r<4;r++){
      const int t = qw0 + g*4 + r;
      const int ka = k0 + li;
      const int kb2 = ka + 16;
      const bool v0 = (ka <= t) && (ka > t - w);
      const bool v1 = (kb2 <= t) && (kb2 > t - w);
      const float p0 = v0 ? __expf(s0[r]*0.125f) : 0.f;
      const float p1 = v1 ? __expf(s1[r]*0.125f) : 0.f;
      lsum[r] += p0 + p1;
      const int q = g*4 + r;
      lP[wid][q*40 + li]      = f2bf(p0);
      lP[wid][q*40 + 16 + li] = f2bf(p1);
    }
    // wave-local LDS bounce (lgkmcnt-ordered, no barrier)
    const bf16x8 pa = *reinterpret_cast<const bf16x8*>(&lP[wid][li*40 + g*8]);
    #pragma unroll
    for (int d4=0; d4<4; d4++)
      oacc[d4] = MFMA16(pa, bv[d4], oacc[d4]);
    #pragma unroll
    for (int i=0;i<4;i++) kf[i] = kn[i];
  }

  // one final cross-lane sum reduce over li (4 rounds)
  #pragma unroll
  for (int msk=1; msk<16; msk<<=1){
    #pragma unroll
    for (int r=0;r<4;r++) lsum[r] += __shfl_xor(lsum[r], msk, 64);
  }

  if (partial){
    unsigned short* po = pO + (size_t)slot*16*64;
    #pragma unroll
    for (int r2=0;r2<4;r2++){
      const int row = g*4 + r2;
      #pragma unroll
      for (int d4=0; d4<4; d4++) po[row*64 + d4*16 + li] = f2bf(oacc[d4][r2]);
    }
    if (li == 0){
      #pragma unroll
      for (int r2=0;r2<4;r2++) pL[(size_t)slot*16 + g*4 + r2] = lsum[r2];
    }
  } else {
    #pragma unroll
    for (int r=0;r<4;r++){
      const int t = qw0 + g*4 + r;
      const float gv = gates[(size_t)(b*T_SEQ + t)*NH + h];
      const float inv = gv / lsum[r];
      unsigned short* orow = gated + (size_t)(b*T_SEQ + t)*CEMB + h*64 + li;
      orow[0]  = f2bf(oacc[0][r]*inv);
      orow[16] = f2bf(oacc[1][r]*inv);
      orow[32] = f2bf(oacc[2][r]*inv);
      orow[48] = f2bf(oacc[3][r]*inv);
    }
  }
}

// ---------------- merge partials for h=0,1 (plain sums, no exp) ----------------
__global__ __launch_bounds__(256)
void attn_merge_kernel(const unsigned short* __restrict__ pO, const float* __restrict__ pL,
                       const float* __restrict__ gates, unsigned short* __restrict__ gated){
  const int wid = threadIdx.x>>6, lane = threadIdx.x&63;
  const int W = blockIdx.x*4 + wid;     // [0,512)
  const int h = W>>8;
  const int r = W&255;
  const int b = r>>6, qw16 = r&63;
  const int nch = (h==0) ? 4 : 2;
  const int sb  = (h==0) ? 0 : 4;
  const int slot0 = (b*64 + qw16)*6 + sb;
  for (int row=0; row<16; ++row){
    const int t = qw16*16 + row;
    float L = 0.f, acc = 0.f;
    #pragma unroll
    for (int c2=0;c2<4;c2++){
      if (c2 < nch){
        L   += pL[(size_t)(slot0+c2)*16 + row];
        acc += bf2f(pO[((size_t)(slot0+c2)*16 + row)*64 + lane]);
      }
    }
    const float gv = gates[(size_t)(b*T_SEQ + t)*NH + h];
    gated[(size_t)(b*T_SEQ + t)*CEMB + h*64 + lane] = f2bf(acc * gv / L);
  }
}

extern "C" void kernel_launch(void* const* d_in, const int* in_sizes, int n_in,
                              void* d_out, int out_size, void* d_ws, size_t ws_size,
                              hipStream_t stream){
  const float* x     = (const float*)d_in[0];
  const float* Wqk   = (const float*)d_in[1];
  const float* bqk   = (const float*)d_in[2];
  const float* Wgate = (const float*)d_in[3];
  const float* bgate = (const float*)d_in[4];
  const float* Wproj = (const float*)d_in[5];
  const float* bproj = (const float*)d_in[6];
  float* out = (float*)d_out;

  // workspace layout (~56MB of the 256MB ws)
  unsigned short* x_bf   = (unsigned short*)d_ws;                 // 8MB
  unsigned short* WqkT   = x_bf   + (size_t)4096*1024;            // 4MB
  unsigned short* WprojT = WqkT   + (size_t)2048*1024;            // 2MB
  unsigned short* qkb    = WprojT + (size_t)1024*1024;            // 16MB
  unsigned short* gated  = qkb    + (size_t)4096*2048;            // 8MB
  float*          gates  = (float*)(gated + (size_t)4096*1024);   // 256KB
  unsigned short* pO     = WqkT;                                  // alias (dead after gemm1)
  float*          pL     = (float*)(WqkT + (size_t)4*64*6*16*64);
  unsigned short* Kpack  = (unsigned short*)((char*)d_ws + (size_t)40*1024*1024);  // 8MB
  unsigned short* Vpack  = Kpack + (size_t)64*32*4*512;                            // 8MB

  prep2_kernel<<<1024, 256, 0, stream>>>(x, Wgate, bgate, x_bf, gates);
  wtrans_kernel<<<3072, dim3(32,8), 0, stream>>>(Wqk, WqkT, Wproj, WprojT);

  gemm_bt_kernel<true, 64><<<1024, 256, 0, stream>>>(x_bf,  WqkT,   bqk,   qkb, 4096, 2048, 1024);
  kpack_kernel<<<1024, 256, 0, stream>>>(qkb, Kpack, Vpack);
  attn_mfma_kernel<<<1280, 256, 0, stream>>>(qkb, Kpack, Vpack, gates, gated, pO, pL);
  attn_merge_kernel<<<128, 256, 0, stream>>>(pO, pL, gates, gated);
  gemm_bt_kernel<false, 64><<<512, 256, 0, stream>>>(gated, WprojT, bproj, out, 4096, 1024, 1024);
}

// Round 12
// 103.508 us; speedup vs baseline: 1.1001x; 1.1001x over previous
//
#include <hip/hip_runtime.h>

typedef __attribute__((ext_vector_type(8))) short bf16x8;
typedef __attribute__((ext_vector_type(4))) float f32x4;

#define T_SEQ 1024
#define NH 16
#define CEMB 1024

__device__ __forceinline__ float asf(unsigned int u){ union{unsigned int i;float f;}x; x.i=u; return x.f; }
__device__ __forceinline__ float bf2f(unsigned short u){ return asf(((unsigned int)u)<<16); }
__device__ __forceinline__ unsigned short f2bf(float f){
  union{float f;unsigned int i;}x; x.f=f;
  unsigned int r = x.i + 0x7FFFu + ((x.i>>16)&1u);
  return (unsigned short)(r>>16);
}
__device__ __forceinline__ f32x4 MFMA16(bf16x8 a, bf16x8 b, f32x4 c){
  return __builtin_amdgcn_mfma_f32_16x16x32_bf16(a, b, c, 0,0,0);
}

// ---------------- fp32 -> bf16 convert (vectorized) ----------------
__global__ void cvt_bf16_kernel(const float* __restrict__ in, unsigned short* __restrict__ out, int n){
  int i = (blockIdx.x*blockDim.x + threadIdx.x)*4;
  if (i >= n) return;
  float4 v = *reinterpret_cast<const float4*>(in + i);
  ushort4 o; o.x=f2bf(v.x); o.y=f2bf(v.y); o.z=f2bf(v.z); o.w=f2bf(v.w);
  *reinterpret_cast<ushort4*>(out + i) = o;
}

// ---------------- gates: softmax(x @ Wgate + bgate) over H ----------------
__global__ void gates_kernel(const float* __restrict__ x, const float* __restrict__ Wg,
                             const float* __restrict__ bg, float* __restrict__ gates){
  const int lane = threadIdx.x & 63;
  const int row  = blockIdx.x*4 + (threadIdx.x>>6);
  const float* xr = x + (size_t)row*CEMB;
  float acc[NH];
  #pragma unroll
  for (int h=0;h<NH;h++) acc[h]=0.f;
  for (int i=0;i<CEMB/64;i++){
    float xv = xr[i*64 + lane];
    const float4* wg = reinterpret_cast<const float4*>(Wg + (size_t)(i*64+lane)*NH);
    float4 a=wg[0], b=wg[1], c=wg[2], d=wg[3];
    acc[0]+=xv*a.x; acc[1]+=xv*a.y; acc[2]+=xv*a.z; acc[3]+=xv*a.w;
    acc[4]+=xv*b.x; acc[5]+=xv*b.y; acc[6]+=xv*b.z; acc[7]+=xv*b.w;
    acc[8]+=xv*c.x; acc[9]+=xv*c.y; acc[10]+=xv*c.z; acc[11]+=xv*c.w;
    acc[12]+=xv*d.x; acc[13]+=xv*d.y; acc[14]+=xv*d.z; acc[15]+=xv*d.w;
  }
  #pragma unroll
  for (int h=0;h<NH;h++){
    #pragma unroll
    for (int m=32;m;m>>=1) acc[h] += __shfl_xor(acc[h], m, 64);
  }
  float mx = -1e30f;
  #pragma unroll
  for (int h=0;h<NH;h++){ acc[h] += bg[h]; mx = fmaxf(mx, acc[h]); }
  float s = 0.f;
  #pragma unroll
  for (int h=0;h<NH;h++){ acc[h] = __expf(acc[h]-mx); s += acc[h]; }
  float g = 0.f;
  #pragma unroll
  for (int h=0;h<NH;h++) g = (lane==h) ? acc[h]/s : g;
  if (lane < NH) gates[(size_t)row*NH + lane] = g;
}

// ---------------- both weight transposes, one launch (blockIdx-partitioned) ----------------
__global__ void wtrans_kernel(const float* __restrict__ Wqk, unsigned short* __restrict__ WqkT,
                              const float* __restrict__ Wproj, unsigned short* __restrict__ WprojT){
  __shared__ float tile[32][33];
  int blk = blockIdx.x;
  const float* W; unsigned short* Wt; int R, C, bx, by;
  if (blk < 2048){ W = Wqk;   Wt = WqkT;   R = 1024; C = 2048; bx = blk & 63; by = blk >> 6; }
  else { blk -= 2048; W = Wproj; Wt = WprojT; R = 1024; C = 1024; bx = blk & 31; by = blk >> 5; }
  const int c0 = bx*32, r0 = by*32;
  const int tx = threadIdx.x, ty = threadIdx.y;   // (32,8)
  #pragma unroll
  for (int i=0;i<32;i+=8) tile[ty+i][tx] = W[(size_t)(r0+ty+i)*C + c0 + tx];
  __syncthreads();
  #pragma unroll
  for (int i=0;i<32;i+=8) Wt[(size_t)(c0+ty+i)*R + r0 + tx] = f2bf(tile[tx][ty+i]);
}

// ---------------- bf16 MFMA GEMM: C[M][N] = A[M][K] @ Bt[N][K]^T + bias ----------------
// Double-buffered stage-ahead (2-phase). BM template: 128 (waves 2x2, 64x64 each)
// or 64 (waves 1x4, 64x32 each; 48KB LDS -> 3 blocks/CU).
template<bool OUT_BF16, int BM>
__global__ __launch_bounds__(256)
void gemm_bt_kernel(const unsigned short* __restrict__ A, const unsigned short* __restrict__ Bt,
                    const float* __restrict__ bias, void* __restrict__ Cptr,
                    int M, int N, int K){
  constexpr int WCN   = (BM==128) ? 2 : 4;       // wave cols
  constexpr int MFRAG = 4;                        // 16-row frags per wave
  constexpr int NFRAG = 4/(WCN/2);               // 128/WCN/16
  constexpr int WCW   = 128/WCN;                 // wave col width
  constexpr int AISS  = BM/32;                   // A stage issues
  __shared__ unsigned short lA0[BM*64], lA1[BM*64];
  __shared__ unsigned short lB0[128*64], lB1[128*64];
  const int tid = threadIdx.x;
  const int wid = tid>>6, lane = tid&63;
  const int nbm = M/BM;
  const int bid = blockIdx.x;
  const int bm = bid % nbm, bn = bid / nbm;
  const int wr = (BM==128) ? (wid>>1) : 0;
  const int wc = (BM==128) ? (wid&1) : wid;
  f32x4 acc[MFRAG][NFRAG] = {};

  const unsigned short* gA = A + (size_t)bm*BM*K;
  const unsigned short* gB = Bt + (size_t)bn*128*K;
  const int srow = lane>>3;
  const int schunk = lane&7;

#define GSTAGE(LA, LB, KK) do { \
  _Pragma("unroll") \
  for (int i_=0;i_<AISS;i_++){ \
    int rowi_ = (wid*AISS+i_)*8 + srow; \
    int cc_ = schunk ^ (rowi_ & 7); \
    __builtin_amdgcn_global_load_lds((const __attribute__((address_space(1))) void*)(gA + (size_t)rowi_*K + (KK) + cc_*8), \
        (__attribute__((address_space(3))) void*)&LA[(wid*AISS+i_)*512], 16, 0, 0); \
  } \
  _Pragma("unroll") \
  for (int i_=0;i_<4;i_++){ \
    int rowi_ = (wid*4+i_)*8 + srow; \
    int cc_ = schunk ^ (rowi_ & 7); \
    __builtin_amdgcn_global_load_lds((const __attribute__((address_space(1))) void*)(gB + (size_t)rowi_*K + (KK) + cc_*8), \
        (__attribute__((address_space(3))) void*)&LB[(wid*4+i_)*512], 16, 0, 0); \
  } \
} while(0)

#define GCOMPUTE(LA, LB) do { \
  _Pragma("unroll") \
  for (int ks_=0; ks_<2; ks_++){ \
    bf16x8 af_[MFRAG], bf_[NFRAG]; \
    _Pragma("unroll") \
    for (int m_=0;m_<MFRAG;m_++){ \
      int r_ = wr*64 + m_*16 + (lane&15); \
      int p_ = (ks_*4 + (lane>>4)) ^ (r_&7); \
      af_[m_] = *reinterpret_cast<const bf16x8*>(&LA[r_*64 + p_*8]); \
    } \
    _Pragma("unroll") \
    for (int n_=0;n_<NFRAG;n_++){ \
      int r_ = wc*WCW + n_*16 + (lane&15); \
      int p_ = (ks_*4 + (lane>>4)) ^ (r_&7); \
      bf_[n_] = *reinterpret_cast<const bf16x8*>(&LB[r_*64 + p_*8]); \
    } \
    _Pragma("unroll") \
    for (int m_=0;m_<MFRAG;m_++) \
      _Pragma("unroll") \
      for (int n_=0;n_<NFRAG;n_++) \
        acc[m_][n_] = __builtin_amdgcn_mfma_f32_16x16x32_bf16(af_[m_], bf_[n_], acc[m_][n_], 0,0,0); \
  } \
} while(0)

  GSTAGE(lA0, lB0, 0);
  __syncthreads();
  for (int k0=0; k0<K; k0+=128){
    GSTAGE(lA1, lB1, k0+64);     // issue next-half loads, no wait
    GCOMPUTE(lA0, lB0);          // MFMA on current (hides stage latency)
    __syncthreads();             // drain (after compute) + publish lA1/lB1
    if (k0+128 < K) GSTAGE(lA0, lB0, k0+128);
    GCOMPUTE(lA1, lB1);
    __syncthreads();
  }
#undef GSTAGE
#undef GCOMPUTE

  const int rq = lane>>4;
  const int cl = lane&15;
  #pragma unroll
  for (int n=0;n<NFRAG;n++){
    int col = bn*128 + wc*WCW + n*16 + cl;
    float bv = bias[col];
    #pragma unroll
    for (int m=0;m<MFRAG;m++){
      int row = bm*BM + wr*64 + m*16 + rq*4;
      #pragma unroll
      for (int r=0;r<4;r++){
        float v = acc[m][n][r] + bv;
        if (OUT_BF16) ((unsigned short*)Cptr)[(size_t)(row+r)*N + col] = f2bf(v);
        else          ((float*)Cptr)[(size_t)(row+r)*N + col] = v;
      }
    }
  }
}

// ---------------- fragment pack: K rows -> Kpack (QK B-frags) + Vpack (PV B-frags) ----------------
__global__ __launch_bounds__(256)
void kpack_kernel(const unsigned short* __restrict__ qk,
                  unsigned short* __restrict__ Kpack, unsigned short* __restrict__ Vpack){
  __shared__ unsigned short lT[64][68];
  const int blk = blockIdx.x;          // 1024 = 64 bh * 16 tgroups
  const int t0 = (blk & 15) * 64;
  const int bh = blk >> 4;
  const int b = bh >> 4, h = bh & 15;
  const int tid = threadIdx.x;
  #pragma unroll
  for (int it=0; it<2; it++){
    int idx = tid + it*256;
    int row = idx >> 3, c = idx & 7;
    uint4 v = *reinterpret_cast<const uint4*>(qk + ((size_t)(b*T_SEQ + t0 + row)*2048 + 1024 + h*64 + c*8));
    *reinterpret_cast<uint4*>(&lT[row][c*8]) = v;
  }
  __syncthreads();
  const int wid = tid>>6, lane = tid&63;
  const int g = lane>>4, li = lane&15;
  const int tile = wid>>1;             // 0..1 (32-row tile within the 64 staged rows)
  const int kt = (t0>>5) + tile;
  #pragma unroll
  for (int ff=0; ff<2; ff++){
    const int f = (wid&1)*2 + ff;
    const int row = tile*32 + ((f>>1)<<4) + li;
    const int col = (f&1)*32 + g*8;
    uint4 v = *reinterpret_cast<const uint4*>(&lT[row][col]);
    *reinterpret_cast<uint4*>(Kpack + ((((size_t)bh*32 + kt)*4 + f)*64 + lane)*8) = v;
  }
  #pragma unroll
  for (int ff=0; ff<2; ff++){
    const int d4 = (wid&1)*2 + ff;
    unsigned short vv[8];
    #pragma unroll
    for (int j=0;j<8;j++) vv[j] = lT[tile*32 + g*8 + j][d4*16 + li];
    *reinterpret_cast<uint4*>(Vpack + ((((size_t)bh*32 + kt)*4 + d4)*64 + lane)*8) = *reinterpret_cast<const uint4*>(vv);
  }
}

// ---------------- MFMA attention, no-max softmax, packed frags, NO split-K ----------------
// 4096 waves (one per b,h,16-q-rows), grid 1024 x 4 waves.
// Stride wave mapping V = wid*1024 + blockIdx: every block gets one heavy (h<4)
// wave + three light ones -> all CUs loaded through the tail, 16 waves/CU.
__global__ __launch_bounds__(256)
void attn_mfma_kernel(const unsigned short* __restrict__ qk,
                      const unsigned short* __restrict__ Kpack,
                      const unsigned short* __restrict__ Vpack,
                      const float* __restrict__ gates, unsigned short* __restrict__ gated){
  __shared__ unsigned short lP[4][16*40];
  const int tid = threadIdx.x;
  const int wid = tid>>6, lane = tid&63;
  const int g = lane>>4, li = lane&15;

  const int V = wid*1024 + blockIdx.x;   // [0,4096)
  const int h = V>>8;
  const int rr = V&255;
  const int b = rr>>6, qw16 = rr&63;

  int w = 1024 >> h; if (w < 4) w = 4;
  const int qw0 = qw16*16;
  const int bh = b*NH + h;

  int mylo = qw0 - w + 1; if (mylo < 0) mylo = 0;
  const int kt_start = mylo >> 5;
  const int kt_end = (qw0 + 15) >> 5;

  // Q A-fragments (once per wave)
  const unsigned short* qbase = qk + ((size_t)(b*T_SEQ + qw0 + li)*2048 + h*64 + g*8);
  const bf16x8 aq0 = *reinterpret_cast<const bf16x8*>(qbase);
  const bf16x8 aq1 = *reinterpret_cast<const bf16x8*>(qbase + 32);

  f32x4 oacc[4] = {};
  float lsum[4] = {0.f,0.f,0.f,0.f};

  const unsigned short* kp = Kpack + (size_t)bh*32*4*512;
  const unsigned short* vp = Vpack + (size_t)bh*32*4*512;
  const int loff = lane*8;

  bf16x8 kf[4], kn[4], bv[4];
  #pragma unroll
  for (int f=0; f<4; f++)
    kf[f] = *reinterpret_cast<const bf16x8*>(kp + (kt_start*4 + f)*512 + loff);

  for (int kt = kt_start; kt <= kt_end; ++kt){
    // V frags (current tile), coalesced; issued early, consumed after exp
    #pragma unroll
    for (int d4=0; d4<4; d4++)
      bv[d4] = *reinterpret_cast<const bf16x8*>(vp + (kt*4 + d4)*512 + loff);
    // prefetch next K frags (clamped, branch-free)
    {
      const int ktn = (kt < kt_end) ? kt+1 : kt_end;
      #pragma unroll
      for (int f=0; f<4; f++)
        kn[f] = *reinterpret_cast<const bf16x8*>(kp + (ktn*4 + f)*512 + loff);
    }

    // ---- QK^T ----
    f32x4 s0 = {}, s1 = {};
    s0 = MFMA16(aq0, kf[0], s0);
    s0 = MFMA16(aq1, kf[1], s0);
    s1 = MFMA16(aq0, kf[2], s1);
    s1 = MFMA16(aq1, kf[3], s1);

    // ---- no-max softmax accumulate: p = valid ? exp(s/8) : 0 ----
    const int k0 = kt*32;
    #pragma unroll
    for (int r=0;r<4;r++){
      const int t = qw0 + g*4 + r;
      const int ka = k0 + li;
      const int kb2 = ka + 16;
      const bool v0 = (ka <= t) && (ka > t - w);
      const bool v1 = (kb2 <= t) && (kb2 > t - w);
      const float p0 = v0 ? __expf(s0[r]*0.125f) : 0.f;
      const float p1 = v1 ? __expf(s1[r]*0.125f) : 0.f;
      lsum[r] += p0 + p1;
      const int q = g*4 + r;
      lP[wid][q*40 + li]      = f2bf(p0);
      lP[wid][q*40 + 16 + li] = f2bf(p1);
    }
    // wave-local LDS bounce (lgkmcnt-ordered, no barrier)
    const bf16x8 pa = *reinterpret_cast<const bf16x8*>(&lP[wid][li*40 + g*8]);
    #pragma unroll
    for (int d4=0; d4<4; d4++)
      oacc[d4] = MFMA16(pa, bv[d4], oacc[d4]);
    #pragma unroll
    for (int i=0;i<4;i++) kf[i] = kn[i];
  }

  // one final cross-lane sum reduce over li (4 rounds)
  #pragma unroll
  for (int msk=1; msk<16; msk<<=1){
    #pragma unroll
    for (int r=0;r<4;r++) lsum[r] += __shfl_xor(lsum[r], msk, 64);
  }

  #pragma unroll
  for (int r=0;r<4;r++){
    const int t = qw0 + g*4 + r;
    const float gv = gates[(size_t)(b*T_SEQ + t)*NH + h];
    const float inv = gv / lsum[r];
    unsigned short* orow = gated + (size_t)(b*T_SEQ + t)*CEMB + h*64 + li;
    orow[0]  = f2bf(oacc[0][r]*inv);
    orow[16] = f2bf(oacc[1][r]*inv);
    orow[32] = f2bf(oacc[2][r]*inv);
    orow[48] = f2bf(oacc[3][r]*inv);
  }
}

extern "C" void kernel_launch(void* const* d_in, const int* in_sizes, int n_in,
                              void* d_out, int out_size, void* d_ws, size_t ws_size,
                              hipStream_t stream){
  const float* x     = (const float*)d_in[0];
  const float* Wqk   = (const float*)d_in[1];
  const float* bqk   = (const float*)d_in[2];
  const float* Wgate = (const float*)d_in[3];
  const float* bgate = (const float*)d_in[4];
  const float* Wproj = (const float*)d_in[5];
  const float* bproj = (const float*)d_in[6];
  float* out = (float*)d_out;

  // workspace layout (~56MB of the 256MB ws)
  unsigned short* x_bf   = (unsigned short*)d_ws;                 // 8MB
  unsigned short* WqkT   = x_bf   + (size_t)4096*1024;            // 4MB
  unsigned short* WprojT = WqkT   + (size_t)2048*1024;            // 2MB
  unsigned short* qkb    = WprojT + (size_t)1024*1024;            // 16MB
  unsigned short* gated  = qkb    + (size_t)4096*2048;            // 8MB
  float*          gates  = (float*)(gated + (size_t)4096*1024);   // 256KB
  unsigned short* Kpack  = (unsigned short*)((char*)d_ws + (size_t)40*1024*1024);  // 8MB
  unsigned short* Vpack  = Kpack + (size_t)64*32*4*512;                            // 8MB

  cvt_bf16_kernel<<<4096, 256, 0, stream>>>(x, x_bf, 4096*1024);
  wtrans_kernel<<<3072, dim3(32,8), 0, stream>>>(Wqk, WqkT, Wproj, WprojT);
  gates_kernel<<<1024, 256, 0, stream>>>(x, Wgate, bgate, gates);

  gemm_bt_kernel<true, 128><<<512, 256, 0, stream>>>(x_bf,  WqkT,   bqk,   qkb, 4096, 2048, 1024);
  kpack_kernel<<<1024, 256, 0, stream>>>(qkb, Kpack, Vpack);
  attn_mfma_kernel<<<1024, 256, 0, stream>>>(qkb, Kpack, Vpack, gates, gated);
  gemm_bt_kernel<false, 64><<<512, 256, 0, stream>>>(gated, WprojT, bproj, out, 4096, 1024, 1024);
}

// Round 13
// 101.397 us; speedup vs baseline: 1.1230x; 1.0208x over previous
//
#include <hip/hip_runtime.h>

typedef __attribute__((ext_vector_type(8))) short bf16x8;
typedef __attribute__((ext_vector_type(4))) float f32x4;

#define T_SEQ 1024
#define NH 16
#define CEMB 1024

__device__ __forceinline__ float asf(unsigned int u){ union{unsigned int i;float f;}x; x.i=u; return x.f; }
__device__ __forceinline__ float bf2f(unsigned short u){ return asf(((unsigned int)u)<<16); }
__device__ __forceinline__ unsigned short f2bf(float f){
  union{float f;unsigned int i;}x; x.f=f;
  unsigned int r = x.i + 0x7FFFu + ((x.i>>16)&1u);
  return (unsigned short)(r>>16);
}
__device__ __forceinline__ f32x4 MFMA16(bf16x8 a, bf16x8 b, f32x4 c){
  return __builtin_amdgcn_mfma_f32_16x16x32_bf16(a, b, c, 0,0,0);
}

// ---------------- fp32 -> bf16 convert (vectorized) ----------------
__global__ void cvt_bf16_kernel(const float* __restrict__ in, unsigned short* __restrict__ out, int n){
  int i = (blockIdx.x*blockDim.x + threadIdx.x)*4;
  if (i >= n) return;
  float4 v = *reinterpret_cast<const float4*>(in + i);
  ushort4 o; o.x=f2bf(v.x); o.y=f2bf(v.y); o.z=f2bf(v.z); o.w=f2bf(v.w);
  *reinterpret_cast<ushort4*>(out + i) = o;
}

// ---------------- gates: softmax(x @ Wgate + bgate) over H ----------------
__global__ void gates_kernel(const float* __restrict__ x, const float* __restrict__ Wg,
                             const float* __restrict__ bg, float* __restrict__ gates){
  const int lane = threadIdx.x & 63;
  const int row  = blockIdx.x*4 + (threadIdx.x>>6);
  const float* xr = x + (size_t)row*CEMB;
  float acc[NH];
  #pragma unroll
  for (int h=0;h<NH;h++) acc[h]=0.f;
  for (int i=0;i<CEMB/64;i++){
    float xv = xr[i*64 + lane];
    const float4* wg = reinterpret_cast<const float4*>(Wg + (size_t)(i*64+lane)*NH);
    float4 a=wg[0], b=wg[1], c=wg[2], d=wg[3];
    acc[0]+=xv*a.x; acc[1]+=xv*a.y; acc[2]+=xv*a.z; acc[3]+=xv*a.w;
    acc[4]+=xv*b.x; acc[5]+=xv*b.y; acc[6]+=xv*b.z; acc[7]+=xv*b.w;
    acc[8]+=xv*c.x; acc[9]+=xv*c.y; acc[10]+=xv*c.z; acc[11]+=xv*c.w;
    acc[12]+=xv*d.x; acc[13]+=xv*d.y; acc[14]+=xv*d.z; acc[15]+=xv*d.w;
  }
  #pragma unroll
  for (int h=0;h<NH;h++){
    #pragma unroll
    for (int m=32;m;m>>=1) acc[h] += __shfl_xor(acc[h], m, 64);
  }
  float mx = -1e30f;
  #pragma unroll
  for (int h=0;h<NH;h++){ acc[h] += bg[h]; mx = fmaxf(mx, acc[h]); }
  float s = 0.f;
  #pragma unroll
  for (int h=0;h<NH;h++){ acc[h] = __expf(acc[h]-mx); s += acc[h]; }
  float g = 0.f;
  #pragma unroll
  for (int h=0;h<NH;h++) g = (lane==h) ? acc[h]/s : g;
  if (lane < NH) gates[(size_t)row*NH + lane] = g;
}

// ---------------- both weight transposes, one launch (blockIdx-partitioned) ----------------
__global__ void wtrans_kernel(const float* __restrict__ Wqk, unsigned short* __restrict__ WqkT,
                              const float* __restrict__ Wproj, unsigned short* __restrict__ WprojT){
  __shared__ float tile[32][33];
  int blk = blockIdx.x;
  const float* W; unsigned short* Wt; int R, C, bx, by;
  if (blk < 2048){ W = Wqk;   Wt = WqkT;   R = 1024; C = 2048; bx = blk & 63; by = blk >> 6; }
  else { blk -= 2048; W = Wproj; Wt = WprojT; R = 1024; C = 1024; bx = blk & 31; by = blk >> 5; }
  const int c0 = bx*32, r0 = by*32;
  const int tx = threadIdx.x, ty = threadIdx.y;   // (32,8)
  #pragma unroll
  for (int i=0;i<32;i+=8) tile[ty+i][tx] = W[(size_t)(r0+ty+i)*C + c0 + tx];
  __syncthreads();
  #pragma unroll
  for (int i=0;i<32;i+=8) Wt[(size_t)(c0+ty+i)*R + r0 + tx] = f2bf(tile[tx][ty+i]);
}

// ---------------- bf16 MFMA GEMM: C[M][N] = A[M][K] @ Bt[N][K]^T + bias ----------------
// Depth-2 counted-vmcnt pipeline (T3+T4): two K-half tiles in flight; per tile
// {vmcnt(L); s_barrier; COMPUTE; s_barrier; STAGE(t+2)} — next tile's loads stay
// in flight across the barrier (never drain to 0 in the main loop).
template<bool OUT_BF16, int BM>
__global__ __launch_bounds__(256)
void gemm_bt_kernel(const unsigned short* __restrict__ A, const unsigned short* __restrict__ Bt,
                    const float* __restrict__ bias, void* __restrict__ Cptr,
                    int M, int N, int K){
  constexpr int WCN   = (BM==128) ? 2 : 4;       // wave cols
  constexpr int MFRAG = 4;                        // 16-row frags per wave
  constexpr int NFRAG = 4/(WCN/2);               // 128/WCN/16
  constexpr int WCW   = 128/WCN;                 // wave col width
  constexpr int AISS  = BM/32;                   // A stage issues (per wave)
  __shared__ unsigned short lA0[BM*64], lA1[BM*64];
  __shared__ unsigned short lB0[128*64], lB1[128*64];
  const int tid = threadIdx.x;
  const int wid = tid>>6, lane = tid&63;
  const int nbm = M/BM;
  const int bid = blockIdx.x;
  const int bm = bid % nbm, bn = bid / nbm;
  const int wr = (BM==128) ? (wid>>1) : 0;
  const int wc = (BM==128) ? (wid&1) : wid;
  f32x4 acc[MFRAG][NFRAG] = {};

  const unsigned short* gA = A + (size_t)bm*BM*K;
  const unsigned short* gB = Bt + (size_t)bn*128*K;
  const int srow = lane>>3;
  const int schunk = lane&7;

#define GSTAGE(LA, LB, KK) do { \
  _Pragma("unroll") \
  for (int i_=0;i_<AISS;i_++){ \
    int rowi_ = (wid*AISS+i_)*8 + srow; \
    int cc_ = schunk ^ (rowi_ & 7); \
    __builtin_amdgcn_global_load_lds((const __attribute__((address_space(1))) void*)(gA + (size_t)rowi_*K + (KK) + cc_*8), \
        (__attribute__((address_space(3))) void*)&LA[(wid*AISS+i_)*512], 16, 0, 0); \
  } \
  _Pragma("unroll") \
  for (int i_=0;i_<4;i_++){ \
    int rowi_ = (wid*4+i_)*8 + srow; \
    int cc_ = schunk ^ (rowi_ & 7); \
    __builtin_amdgcn_global_load_lds((const __attribute__((address_space(1))) void*)(gB + (size_t)rowi_*K + (KK) + cc_*8), \
        (__attribute__((address_space(3))) void*)&LB[(wid*4+i_)*512], 16, 0, 0); \
  } \
} while(0)

#define GCOMPUTE(LA, LB) do { \
  _Pragma("unroll") \
  for (int ks_=0; ks_<2; ks_++){ \
    bf16x8 af_[MFRAG], bf_[NFRAG]; \
    _Pragma("unroll") \
    for (int m_=0;m_<MFRAG;m_++){ \
      int r_ = wr*64 + m_*16 + (lane&15); \
      int p_ = (ks_*4 + (lane>>4)) ^ (r_&7); \
      af_[m_] = *reinterpret_cast<const bf16x8*>(&LA[r_*64 + p_*8]); \
    } \
    _Pragma("unroll") \
    for (int n_=0;n_<NFRAG;n_++){ \
      int r_ = wc*WCW + n_*16 + (lane&15); \
      int p_ = (ks_*4 + (lane>>4)) ^ (r_&7); \
      bf_[n_] = *reinterpret_cast<const bf16x8*>(&LB[r_*64 + p_*8]); \
    } \
    _Pragma("unroll") \
    for (int m_=0;m_<MFRAG;m_++) \
      _Pragma("unroll") \
      for (int n_=0;n_<NFRAG;n_++) \
        acc[m_][n_] = __builtin_amdgcn_mfma_f32_16x16x32_bf16(af_[m_], bf_[n_], acc[m_][n_], 0,0,0); \
  } \
} while(0)

// counted wait: keep the newest L loads (next tile) in flight, ensure older landed
#define WAITL do { \
  if (BM==128) asm volatile("s_waitcnt vmcnt(8)" ::: "memory"); \
  else         asm volatile("s_waitcnt vmcnt(6)" ::: "memory"); \
  __builtin_amdgcn_s_barrier(); \
  __builtin_amdgcn_sched_barrier(0); \
} while(0)

  GSTAGE(lA0, lB0, 0);
  GSTAGE(lA1, lB1, 64);
  for (int k0=0; k0<K-128; k0+=128){
    WAITL;                        // tile k0 landed (next tile stays in flight)
    GCOMPUTE(lA0, lB0);
    __builtin_amdgcn_s_barrier(); // all waves done reading buf0
    __builtin_amdgcn_sched_barrier(0);
    GSTAGE(lA0, lB0, k0+128);
    WAITL;                        // tile k0+64 landed
    GCOMPUTE(lA1, lB1);
    __builtin_amdgcn_s_barrier();
    __builtin_amdgcn_sched_barrier(0);
    GSTAGE(lA1, lB1, k0+192);
  }
  // epilogue: tiles K-128 (buf0) and K-64 (buf1) in flight, no more stages
  WAITL;
  GCOMPUTE(lA0, lB0);
  asm volatile("s_waitcnt vmcnt(0)" ::: "memory");
  __builtin_amdgcn_s_barrier();
  __builtin_amdgcn_sched_barrier(0);
  GCOMPUTE(lA1, lB1);
#undef GSTAGE
#undef GCOMPUTE
#undef WAITL

  const int rq = lane>>4;
  const int cl = lane&15;
  #pragma unroll
  for (int n=0;n<NFRAG;n++){
    int col = bn*128 + wc*WCW + n*16 + cl;
    float bv = bias[col];
    #pragma unroll
    for (int m=0;m<MFRAG;m++){
      int row = bm*BM + wr*64 + m*16 + rq*4;
      #pragma unroll
      for (int r=0;r<4;r++){
        float v = acc[m][n][r] + bv;
        if (OUT_BF16) ((unsigned short*)Cptr)[(size_t)(row+r)*N + col] = f2bf(v);
        else          ((float*)Cptr)[(size_t)(row+r)*N + col] = v;
      }
    }
  }
}

// ---------------- fragment pack: K rows -> Kpack (QK B-frags) + Vpack (PV B-frags) ----------------
__global__ __launch_bounds__(256)
void kpack_kernel(const unsigned short* __restrict__ qk,
                  unsigned short* __restrict__ Kpack, unsigned short* __restrict__ Vpack){
  __shared__ unsigned short lT[64][68];
  const int blk = blockIdx.x;          // 1024 = 64 bh * 16 tgroups
  const int t0 = (blk & 15) * 64;
  const int bh = blk >> 4;
  const int b = bh >> 4, h = bh & 15;
  const int tid = threadIdx.x;
  #pragma unroll
  for (int it=0; it<2; it++){
    int idx = tid + it*256;
    int row = idx >> 3, c = idx & 7;
    uint4 v = *reinterpret_cast<const uint4*>(qk + ((size_t)(b*T_SEQ + t0 + row)*2048 + 1024 + h*64 + c*8));
    *reinterpret_cast<uint4*>(&lT[row][c*8]) = v;
  }
  __syncthreads();
  const int wid = tid>>6, lane = tid&63;
  const int g = lane>>4, li = lane&15;
  const int tile = wid>>1;             // 0..1 (32-row tile within the 64 staged rows)
  const int kt = (t0>>5) + tile;
  #pragma unroll
  for (int ff=0; ff<2; ff++){
    const int f = (wid&1)*2 + ff;
    const int row = tile*32 + ((f>>1)<<4) + li;
    const int col = (f&1)*32 + g*8;
    uint4 v = *reinterpret_cast<const uint4*>(&lT[row][col]);
    *reinterpret_cast<uint4*>(Kpack + ((((size_t)bh*32 + kt)*4 + f)*64 + lane)*8) = v;
  }
  #pragma unroll
  for (int ff=0; ff<2; ff++){
    const int d4 = (wid&1)*2 + ff;
    unsigned short vv[8];
    #pragma unroll
    for (int j=0;j<8;j++) vv[j] = lT[tile*32 + g*8 + j][d4*16 + li];
    *reinterpret_cast<uint4*>(Vpack + ((((size_t)bh*32 + kt)*4 + d4)*64 + lane)*8) = *reinterpret_cast<const uint4*>(vv);
  }
}

// ---------------- MFMA attention, no-max softmax, packed frags, NO split-K ----------------
// Stride wave mapping V = wid*1024 + blockIdx: every block gets one heavy (h<4)
// wave + three light ones -> all CUs loaded through the tail.
__global__ __launch_bounds__(256)
void attn_mfma_kernel(const unsigned short* __restrict__ qk,
                      const unsigned short* __restrict__ Kpack,
                      const unsigned short* __restrict__ Vpack,
                      const float* __restrict__ gates, unsigned short* __restrict__ gated){
  __shared__ unsigned short lP[4][16*40];
  const int tid = threadIdx.x;
  const int wid = tid>>6, lane = tid&63;
  const int g = lane>>4, li = lane&15;

  const int V = wid*1024 + blockIdx.x;   // [0,4096)
  const int h = V>>8;
  const int rr = V&255;
  const int b = rr>>6, qw16 = rr&63;

  int w = 1024 >> h; if (w < 4) w = 4;
  const int qw0 = qw16*16;
  const int bh = b*NH + h;

  int mylo = qw0 - w + 1; if (mylo < 0) mylo = 0;
  const int kt_start = mylo >> 5;
  const int kt_end = (qw0 + 15) >> 5;

  // Q A-fragments (once per wave)
  const unsigned short* qbase = qk + ((size_t)(b*T_SEQ + qw0 + li)*2048 + h*64 + g*8);
  const bf16x8 aq0 = *reinterpret_cast<const bf16x8*>(qbase);
  const bf16x8 aq1 = *reinterpret_cast<const bf16x8*>(qbase + 32);

  f32x4 oacc[4] = {};
  float lsum[4] = {0.f,0.f,0.f,0.f};

  const unsigned short* kp = Kpack + (size_t)bh*32*4*512;
  const unsigned short* vp = Vpack + (size_t)bh*32*4*512;
  const int loff = lane*8;

  bf16x8 kf[4], kn[4], bv[4];
  #pragma unroll
  for (int f=0; f<4; f++)
    kf[f] = *reinterpret_cast<const bf16x8*>(kp + (kt_start*4 + f)*512 + loff);

  for (int kt = kt_start; kt <= kt_end; ++kt){
    // V frags (current tile), coalesced; issued early, consumed after exp
    #pragma unroll
    for (int d4=0; d4<4; d4++)
      bv[d4] = *reinterpret_cast<const bf16x8*>(vp + (kt*4 + d4)*512 + loff);
    // prefetch next K frags (clamped, branch-free)
    {
      const int ktn = (kt < kt_end) ? kt+1 : kt_end;
      #pragma unroll
      for (int f=0; f<4; f++)
        kn[f] = *reinterpret_cast<const bf16x8*>(kp + (ktn*4 + f)*512 + loff);
    }

    // ---- QK^T ----
    f32x4 s0 = {}, s1 = {};
    s0 = MFMA16(aq0, kf[0], s0);
    s0 = MFMA16(aq1, kf[1], s0);
    s1 = MFMA16(aq0, kf[2], s1);
    s1 = MFMA16(aq1, kf[3], s1);

    // ---- no-max softmax accumulate: p = valid ? exp(s/8) : 0 ----
    const int k0 = kt*32;
    #pragma unroll
    for (int r=0;r<4;r++){
      const int t = qw0 + g*4 + r;
      const int ka = k0 + li;
      const int kb2 = ka + 16;
      const bool v0 = (ka <= t) && (ka > t - w);
      const bool v1 = (kb2 <= t) && (kb2 > t - w);
      const float p0 = v0 ? __expf(s0[r]*0.125f) : 0.f;
      const float p1 = v1 ? __expf(s1[r]*0.125f) : 0.f;
      lsum[r] += p0 + p1;
      const int q = g*4 + r;
      lP[wid][q*40 + li]      = f2bf(p0);
      lP[wid][q*40 + 16 + li] = f2bf(p1);
    }
    // wave-local LDS bounce (lgkmcnt-ordered, no barrier)
    const bf16x8 pa = *reinterpret_cast<const bf16x8*>(&lP[wid][li*40 + g*8]);
    #pragma unroll
    for (int d4=0; d4<4; d4++)
      oacc[d4] = MFMA16(pa, bv[d4], oacc[d4]);
    #pragma unroll
    for (int i=0;i<4;i++) kf[i] = kn[i];
  }

  // one final cross-lane sum reduce over li (4 rounds)
  #pragma unroll
  for (int msk=1; msk<16; msk<<=1){
    #pragma unroll
    for (int r=0;r<4;r++) lsum[r] += __shfl_xor(lsum[r], msk, 64);
  }

  #pragma unroll
  for (int r=0;r<4;r++){
    const int t = qw0 + g*4 + r;
    const float gv = gates[(size_t)(b*T_SEQ + t)*NH + h];
    const float inv = gv / lsum[r];
    unsigned short* orow = gated + (size_t)(b*T_SEQ + t)*CEMB + h*64 + li;
    orow[0]  = f2bf(oacc[0][r]*inv);
    orow[16] = f2bf(oacc[1][r]*inv);
    orow[32] = f2bf(oacc[2][r]*inv);
    orow[48] = f2bf(oacc[3][r]*inv);
  }
}

extern "C" void kernel_launch(void* const* d_in, const int* in_sizes, int n_in,
                              void* d_out, int out_size, void* d_ws, size_t ws_size,
                              hipStream_t stream){
  const float* x     = (const float*)d_in[0];
  const float* Wqk   = (const float*)d_in[1];
  const float* bqk   = (const float*)d_in[2];
  const float* Wgate = (const float*)d_in[3];
  const float* bgate = (const float*)d_in[4];
  const float* Wproj = (const float*)d_in[5];
  const float* bproj = (const float*)d_in[6];
  float* out = (float*)d_out;

  // workspace layout (~56MB of the 256MB ws)
  unsigned short* x_bf   = (unsigned short*)d_ws;                 // 8MB
  unsigned short* WqkT   = x_bf   + (size_t)4096*1024;            // 4MB
  unsigned short* WprojT = WqkT   + (size_t)2048*1024;            // 2MB
  unsigned short* qkb    = WprojT + (size_t)1024*1024;            // 16MB
  unsigned short* gated  = qkb    + (size_t)4096*2048;            // 8MB
  float*          gates  = (float*)(gated + (size_t)4096*1024);   // 256KB
  unsigned short* Kpack  = (unsigned short*)((char*)d_ws + (size_t)40*1024*1024);  // 8MB
  unsigned short* Vpack  = Kpack + (size_t)64*32*4*512;                            // 8MB

  cvt_bf16_kernel<<<4096, 256, 0, stream>>>(x, x_bf, 4096*1024);
  wtrans_kernel<<<3072, dim3(32,8), 0, stream>>>(Wqk, WqkT, Wproj, WprojT);
  gates_kernel<<<1024, 256, 0, stream>>>(x, Wgate, bgate, gates);

  gemm_bt_kernel<true, 128><<<512, 256, 0, stream>>>(x_bf,  WqkT,   bqk,   qkb, 4096, 2048, 1024);
  kpack_kernel<<<1024, 256, 0, stream>>>(qkb, Kpack, Vpack);
  attn_mfma_kernel<<<1024, 256, 0, stream>>>(qkb, Kpack, Vpack, gates, gated);
  gemm_bt_kernel<false, 64><<<512, 256, 0, stream>>>(gated, WprojT, bproj, out, 4096, 1024, 1024);
}

// Round 14
// 97.986 us; speedup vs baseline: 1.1621x; 1.0348x over previous
//
#include <hip/hip_runtime.h>

typedef __attribute__((ext_vector_type(8))) short bf16x8;
typedef __attribute__((ext_vector_type(4))) float f32x4;

#define T_SEQ 1024
#define NH 16
#define CEMB 1024

__device__ __forceinline__ float asf(unsigned int u){ union{unsigned int i;float f;}x; x.i=u; return x.f; }
__device__ __forceinline__ float bf2f(unsigned short u){ return asf(((unsigned int)u)<<16); }
__device__ __forceinline__ unsigned short f2bf(float f){
  union{float f;unsigned int i;}x; x.f=f;
  unsigned int r = x.i + 0x7FFFu + ((x.i>>16)&1u);
  return (unsigned short)(r>>16);
}
__device__ __forceinline__ f32x4 MFMA16(bf16x8 a, bf16x8 b, f32x4 c){
  return __builtin_amdgcn_mfma_f32_16x16x32_bf16(a, b, c, 0,0,0);
}

// ---------------- fused prep: cvt (blocks 0-4095) | wtrans (4096-7167) | gates (7168-8191) ----------------
__global__ __launch_bounds__(256)
void prep_all_kernel(const float* __restrict__ x, unsigned short* __restrict__ x_bf,
                     const float* __restrict__ Wqk, unsigned short* __restrict__ WqkT,
                     const float* __restrict__ Wproj, unsigned short* __restrict__ WprojT,
                     const float* __restrict__ Wg, const float* __restrict__ bg,
                     float* __restrict__ gates){
  __shared__ float tile[32][33];
  const int tid = threadIdx.x;
  int blk = blockIdx.x;
  if (blk < 4096){
    // ---- cvt x -> bf16 ----
    int i = (blk*256 + tid)*4;
    float4 v = *reinterpret_cast<const float4*>(x + i);
    ushort4 o; o.x=f2bf(v.x); o.y=f2bf(v.y); o.z=f2bf(v.z); o.w=f2bf(v.w);
    *reinterpret_cast<ushort4*>(x_bf + i) = o;
  } else if (blk < 7168){
    // ---- weight transposes ----
    blk -= 4096;
    const float* W; unsigned short* Wt; int R, C, bx, by;
    if (blk < 2048){ W = Wqk;   Wt = WqkT;   R = 1024; C = 2048; bx = blk & 63; by = blk >> 6; }
    else { blk -= 2048; W = Wproj; Wt = WprojT; R = 1024; C = 1024; bx = blk & 31; by = blk >> 5; }
    const int c0 = bx*32, r0 = by*32;
    const int tx = tid & 31, ty = tid >> 5;   // (32,8)
    #pragma unroll
    for (int i=0;i<32;i+=8) tile[ty+i][tx] = W[(size_t)(r0+ty+i)*C + c0 + tx];
    __syncthreads();
    #pragma unroll
    for (int i=0;i<32;i+=8) Wt[(size_t)(c0+ty+i)*R + r0 + tx] = f2bf(tile[tx][ty+i]);
  } else {
    // ---- gates ----
    const int lane = tid & 63;
    const int row  = (blk-7168)*4 + (tid>>6);
    const float* xr = x + (size_t)row*CEMB;
    float acc[NH];
    #pragma unroll
    for (int h=0;h<NH;h++) acc[h]=0.f;
    for (int i=0;i<CEMB/64;i++){
      float xv = xr[i*64 + lane];
      const float4* wg = reinterpret_cast<const float4*>(Wg + (size_t)(i*64+lane)*NH);
      float4 a=wg[0], b=wg[1], c=wg[2], d=wg[3];
      acc[0]+=xv*a.x; acc[1]+=xv*a.y; acc[2]+=xv*a.z; acc[3]+=xv*a.w;
      acc[4]+=xv*b.x; acc[5]+=xv*b.y; acc[6]+=xv*b.z; acc[7]+=xv*b.w;
      acc[8]+=xv*c.x; acc[9]+=xv*c.y; acc[10]+=xv*c.z; acc[11]+=xv*c.w;
      acc[12]+=xv*d.x; acc[13]+=xv*d.y; acc[14]+=xv*d.z; acc[15]+=xv*d.w;
    }
    #pragma unroll
    for (int h=0;h<NH;h++){
      #pragma unroll
      for (int m=32;m;m>>=1) acc[h] += __shfl_xor(acc[h], m, 64);
    }
    float mx = -1e30f;
    #pragma unroll
    for (int h=0;h<NH;h++){ acc[h] += bg[h]; mx = fmaxf(mx, acc[h]); }
    float s = 0.f;
    #pragma unroll
    for (int h=0;h<NH;h++){ acc[h] = __expf(acc[h]-mx); s += acc[h]; }
    float g = 0.f;
    #pragma unroll
    for (int h=0;h<NH;h++) g = (lane==h) ? acc[h]/s : g;
    if (lane < NH) gates[(size_t)row*NH + lane] = g;
  }
}

// ---------------- bf16 MFMA GEMM with depth-2 counted-vmcnt pipeline ----------------
// PACK=true (gemm1): k-half blocks (bn>=8) emit Kpack/Vpack fragments directly
// from an LDS-staged tile instead of writing row-major C (k-half of qkb was
// only ever read by the old kpack kernel).
template<bool OUT_BF16, int BM, bool PACK>
__global__ __launch_bounds__(256)
void gemm_bt_kernel(const unsigned short* __restrict__ A, const unsigned short* __restrict__ Bt,
                    const float* __restrict__ bias, void* __restrict__ Cptr,
                    int M, int N, int K,
                    unsigned short* __restrict__ Kpack, unsigned short* __restrict__ Vpack){
  constexpr int WCN   = (BM==128) ? 2 : 4;       // wave cols
  constexpr int MFRAG = 4;                        // 16-row frags per wave
  constexpr int NFRAG = 4/(WCN/2);               // 128/WCN/16
  constexpr int WCW   = 128/WCN;                 // wave col width
  constexpr int AISS  = BM/32;                   // A stage issues (per wave)
  constexpr int LDSN  = BM*64*2 + 128*64*2;      // total ushorts (pipeline view)
  __shared__ __align__(16) unsigned short smem[LDSN];
  unsigned short* lA0 = smem;
  unsigned short* lA1 = smem + BM*64;
  unsigned short* lB0 = smem + BM*64*2;
  unsigned short* lB1 = smem + BM*64*2 + 128*64;
  const int tid = threadIdx.x;
  const int wid = tid>>6, lane = tid&63;
  const int nbm = M/BM;
  const int bid = blockIdx.x;
  const int bm = bid % nbm, bn = bid / nbm;
  const int wr = (BM==128) ? (wid>>1) : 0;
  const int wc = (BM==128) ? (wid&1) : wid;
  f32x4 acc[MFRAG][NFRAG] = {};

  const unsigned short* gA = A + (size_t)bm*BM*K;
  const unsigned short* gB = Bt + (size_t)bn*128*K;
  const int srow = lane>>3;
  const int schunk = lane&7;

#define GSTAGE(LA, LB, KK) do { \
  _Pragma("unroll") \
  for (int i_=0;i_<AISS;i_++){ \
    int rowi_ = (wid*AISS+i_)*8 + srow; \
    int cc_ = schunk ^ (rowi_ & 7); \
    __builtin_amdgcn_global_load_lds((const __attribute__((address_space(1))) void*)(gA + (size_t)rowi_*K + (KK) + cc_*8), \
        (__attribute__((address_space(3))) void*)&LA[(wid*AISS+i_)*512], 16, 0, 0); \
  } \
  _Pragma("unroll") \
  for (int i_=0;i_<4;i_++){ \
    int rowi_ = (wid*4+i_)*8 + srow; \
    int cc_ = schunk ^ (rowi_ & 7); \
    __builtin_amdgcn_global_load_lds((const __attribute__((address_space(1))) void*)(gB + (size_t)rowi_*K + (KK) + cc_*8), \
        (__attribute__((address_space(3))) void*)&LB[(wid*4+i_)*512], 16, 0, 0); \
  } \
} while(0)

#define GCOMPUTE(LA, LB) do { \
  _Pragma("unroll") \
  for (int ks_=0; ks_<2; ks_++){ \
    bf16x8 af_[MFRAG], bf_[NFRAG]; \
    _Pragma("unroll") \
    for (int m_=0;m_<MFRAG;m_++){ \
      int r_ = wr*64 + m_*16 + (lane&15); \
      int p_ = (ks_*4 + (lane>>4)) ^ (r_&7); \
      af_[m_] = *reinterpret_cast<const bf16x8*>(&LA[r_*64 + p_*8]); \
    } \
    _Pragma("unroll") \
    for (int n_=0;n_<NFRAG;n_++){ \
      int r_ = wc*WCW + n_*16 + (lane&15); \
      int p_ = (ks_*4 + (lane>>4)) ^ (r_&7); \
      bf_[n_] = *reinterpret_cast<const bf16x8*>(&LB[r_*64 + p_*8]); \
    } \
    _Pragma("unroll") \
    for (int m_=0;m_<MFRAG;m_++) \
      _Pragma("unroll") \
      for (int n_=0;n_<NFRAG;n_++) \
        acc[m_][n_] = __builtin_amdgcn_mfma_f32_16x16x32_bf16(af_[m_], bf_[n_], acc[m_][n_], 0,0,0); \
  } \
} while(0)

#define WAITL do { \
  if (BM==128) asm volatile("s_waitcnt vmcnt(8)" ::: "memory"); \
  else         asm volatile("s_waitcnt vmcnt(6)" ::: "memory"); \
  __builtin_amdgcn_s_barrier(); \
  __builtin_amdgcn_sched_barrier(0); \
} while(0)

  GSTAGE(lA0, lB0, 0);
  GSTAGE(lA1, lB1, 64);
  for (int k0=0; k0<K-128; k0+=128){
    WAITL;
    GCOMPUTE(lA0, lB0);
    __builtin_amdgcn_s_barrier();
    __builtin_amdgcn_sched_barrier(0);
    GSTAGE(lA0, lB0, k0+128);
    WAITL;
    GCOMPUTE(lA1, lB1);
    __builtin_amdgcn_s_barrier();
    __builtin_amdgcn_sched_barrier(0);
    GSTAGE(lA1, lB1, k0+192);
  }
  WAITL;
  GCOMPUTE(lA0, lB0);
  asm volatile("s_waitcnt vmcnt(0)" ::: "memory");
  __builtin_amdgcn_s_barrier();
  __builtin_amdgcn_sched_barrier(0);
  GCOMPUTE(lA1, lB1);
#undef GSTAGE
#undef GCOMPUTE
#undef WAITL

  const int rq = lane>>4;
  const int cl = lane&15;

  if (PACK && bn >= 8){
    // ---- pack epilogue: stage tile (stride 136) then emit Kpack/Vpack frags ----
    __syncthreads();    // all waves done with pipeline LDS reads
    #pragma unroll
    for (int n=0;n<NFRAG;n++){
      const int c_l = wc*WCW + n*16 + cl;
      const float bv = bias[bn*128 + c_l];
      #pragma unroll
      for (int m=0;m<MFRAG;m++){
        const int r_l = wr*64 + m*16 + rq*4;
        #pragma unroll
        for (int r=0;r<4;r++)
          smem[(r_l+r)*136 + c_l] = f2bf(acc[m][n][r] + bv);
      }
    }
    __syncthreads();
    const int b = bm>>3;              // 8 row-blocks per batch
    const int ktg0 = (bm&7)*4;        // first global kt of this tile
    const int g = lane>>4, li = lane&15;
    const int kt_l = wid;             // wave owns one 32-row kt tile
    #pragma unroll
    for (int hh=0; hh<2; hh++){
      const int bh = b*NH + (bn-8)*2 + hh;
      const size_t fb = ((size_t)bh*32 + ktg0 + kt_l)*4;
      #pragma unroll
      for (int f=0; f<4; f++){
        // Kpack[bh][kt][f][lane][j] = K[kt*32+(f>>1)*16+li][(f&1)*32+g*8+j]
        uint4 kv = *reinterpret_cast<const uint4*>(
            &smem[(kt_l*32 + ((f>>1)<<4) + li)*136 + hh*64 + (f&1)*32 + g*8]);
        *reinterpret_cast<uint4*>(Kpack + ((fb + f)*64 + lane)*8) = kv;
        // Vpack[bh][kt][d4][lane][j] = K[kt*32+g*8+j][d4*16+li]   (d4 = f)
        unsigned short vv[8];
        #pragma unroll
        for (int j=0;j<8;j++) vv[j] = smem[(kt_l*32 + g*8 + j)*136 + hh*64 + f*16 + li];
        *reinterpret_cast<uint4*>(Vpack + ((fb + f)*64 + lane)*8) = *reinterpret_cast<const uint4*>(vv);
      }
    }
    return;
  }

  #pragma unroll
  for (int n=0;n<NFRAG;n++){
    int col = bn*128 + wc*WCW + n*16 + cl;
    float bv = bias[col];
    #pragma unroll
    for (int m=0;m<MFRAG;m++){
      int row = bm*BM + wr*64 + m*16 + rq*4;
      #pragma unroll
      for (int r=0;r<4;r++){
        float v = acc[m][n][r] + bv;
        if (OUT_BF16) ((unsigned short*)Cptr)[(size_t)(row+r)*N + col] = f2bf(v);
        else          ((float*)Cptr)[(size_t)(row+r)*N + col] = v;
      }
    }
  }
}

// ---------------- MFMA attention, no-max softmax, packed frags, NO split-K ----------------
// Stride wave mapping V = wid*1024 + blockIdx: every block gets one heavy (h<4)
// wave + three light ones -> all CUs loaded through the tail.
__global__ __launch_bounds__(256)
void attn_mfma_kernel(const unsigned short* __restrict__ qk,
                      const unsigned short* __restrict__ Kpack,
                      const unsigned short* __restrict__ Vpack,
                      const float* __restrict__ gates, unsigned short* __restrict__ gated){
  __shared__ unsigned short lP[4][16*40];
  const int tid = threadIdx.x;
  const int wid = tid>>6, lane = tid&63;
  const int g = lane>>4, li = lane&15;

  const int V = wid*1024 + blockIdx.x;   // [0,4096)
  const int h = V>>8;
  const int rr = V&255;
  const int b = rr>>6, qw16 = rr&63;

  int w = 1024 >> h; if (w < 4) w = 4;
  const int qw0 = qw16*16;
  const int bh = b*NH + h;

  int mylo = qw0 - w + 1; if (mylo < 0) mylo = 0;
  const int kt_start = mylo >> 5;
  const int kt_end = (qw0 + 15) >> 5;

  const unsigned short* qbase = qk + ((size_t)(b*T_SEQ + qw0 + li)*2048 + h*64 + g*8);
  const bf16x8 aq0 = *reinterpret_cast<const bf16x8*>(qbase);
  const bf16x8 aq1 = *reinterpret_cast<const bf16x8*>(qbase + 32);

  f32x4 oacc[4] = {};
  float lsum[4] = {0.f,0.f,0.f,0.f};

  const unsigned short* kp = Kpack + (size_t)bh*32*4*512;
  const unsigned short* vp = Vpack + (size_t)bh*32*4*512;
  const int loff = lane*8;

  bf16x8 kf[4], kn[4], bv[4];
  #pragma unroll
  for (int f=0; f<4; f++)
    kf[f] = *reinterpret_cast<const bf16x8*>(kp + (kt_start*4 + f)*512 + loff);

  for (int kt = kt_start; kt <= kt_end; ++kt){
    #pragma unroll
    for (int d4=0; d4<4; d4++)
      bv[d4] = *reinterpret_cast<const bf16x8*>(vp + (kt*4 + d4)*512 + loff);
    {
      const int ktn = (kt < kt_end) ? kt+1 : kt_end;
      #pragma unroll
      for (int f=0; f<4; f++)
        kn[f] = *reinterpret_cast<const bf16x8*>(kp + (ktn*4 + f)*512 + loff);
    }

    f32x4 s0 = {}, s1 = {};
    s0 = MFMA16(aq0, kf[0], s0);
    s0 = MFMA16(aq1, kf[1], s0);
    s1 = MFMA16(aq0, kf[2], s1);
    s1 = MFMA16(aq1, kf[3], s1);

    const int k0 = kt*32;
    #pragma unroll
    for (int r=0;r<4;r++){
      const int t = qw0 + g*4 + r;
      const int ka = k0 + li;
      const int kb2 = ka + 16;
      const bool v0 = (ka <= t) && (ka > t - w);
      const bool v1 = (kb2 <= t) && (kb2 > t - w);
      const float p0 = v0 ? __expf(s0[r]*0.125f) : 0.f;
      const float p1 = v1 ? __expf(s1[r]*0.125f) : 0.f;
      lsum[r] += p0 + p1;
      const int q = g*4 + r;
      lP[wid][q*40 + li]      = f2bf(p0);
      lP[wid][q*40 + 16 + li] = f2bf(p1);
    }
    const bf16x8 pa = *reinterpret_cast<const bf16x8*>(&lP[wid][li*40 + g*8]);
    #pragma unroll
    for (int d4=0; d4<4; d4++)
      oacc[d4] = MFMA16(pa, bv[d4], oacc[d4]);
    #pragma unroll
    for (int i=0;i<4;i++) kf[i] = kn[i];
  }

  #pragma unroll
  for (int msk=1; msk<16; msk<<=1){
    #pragma unroll
    for (int r=0;r<4;r++) lsum[r] += __shfl_xor(lsum[r], msk, 64);
  }

  #pragma unroll
  for (int r=0;r<4;r++){
    const int t = qw0 + g*4 + r;
    const float gv = gates[(size_t)(b*T_SEQ + t)*NH + h];
    const float inv = gv / lsum[r];
    unsigned short* orow = gated + (size_t)(b*T_SEQ + t)*CEMB + h*64 + li;
    orow[0]  = f2bf(oacc[0][r]*inv);
    orow[16] = f2bf(oacc[1][r]*inv);
    orow[32] = f2bf(oacc[2][r]*inv);
    orow[48] = f2bf(oacc[3][r]*inv);
  }
}

extern "C" void kernel_launch(void* const* d_in, const int* in_sizes, int n_in,
                              void* d_out, int out_size, void* d_ws, size_t ws_size,
                              hipStream_t stream){
  const float* x     = (const float*)d_in[0];
  const float* Wqk   = (const float*)d_in[1];
  const float* bqk   = (const float*)d_in[2];
  const float* Wgate = (const float*)d_in[3];
  const float* bgate = (const float*)d_in[4];
  const float* Wproj = (const float*)d_in[5];
  const float* bproj = (const float*)d_in[6];
  float* out = (float*)d_out;

  // workspace layout (~56MB of the 256MB ws)
  unsigned short* x_bf   = (unsigned short*)d_ws;                 // 8MB
  unsigned short* WqkT   = x_bf   + (size_t)4096*1024;            // 4MB
  unsigned short* WprojT = WqkT   + (size_t)2048*1024;            // 2MB
  unsigned short* qkb    = WprojT + (size_t)1024*1024;            // 16MB (k-half unused)
  unsigned short* gated  = qkb    + (size_t)4096*2048;            // 8MB
  float*          gates  = (float*)(gated + (size_t)4096*1024);   // 256KB
  unsigned short* Kpack  = (unsigned short*)((char*)d_ws + (size_t)40*1024*1024);  // 8MB
  unsigned short* Vpack  = Kpack + (size_t)64*32*4*512;                            // 8MB

  prep_all_kernel<<<8192, 256, 0, stream>>>(x, x_bf, Wqk, WqkT, Wproj, WprojT, Wgate, bgate, gates);

  gemm_bt_kernel<true, 128, true><<<512, 256, 0, stream>>>(x_bf, WqkT, bqk, qkb,
                                                           4096, 2048, 1024, Kpack, Vpack);
  attn_mfma_kernel<<<1024, 256, 0, stream>>>(qkb, Kpack, Vpack, gates, gated);
  gemm_bt_kernel<false, 64, false><<<512, 256, 0, stream>>>(gated, WprojT, bproj, out,
                                                            4096, 1024, 1024, nullptr, nullptr);
}

// Round 15
// 89.208 us; speedup vs baseline: 1.2765x; 1.0984x over previous
//
#include <hip/hip_runtime.h>

typedef __attribute__((ext_vector_type(8))) short bf16x8;
typedef __attribute__((ext_vector_type(4))) float f32x4;

#define T_SEQ 1024
#define NH 16
#define CEMB 1024

__device__ __forceinline__ float asf(unsigned int u){ union{unsigned int i;float f;}x; x.i=u; return x.f; }
__device__ __forceinline__ float bf2f(unsigned short u){ return asf(((unsigned int)u)<<16); }
__device__ __forceinline__ unsigned short f2bf(float f){
  union{float f;unsigned int i;}x; x.f=f;
  unsigned int r = x.i + 0x7FFFu + ((x.i>>16)&1u);
  return (unsigned short)(r>>16);
}
__device__ __forceinline__ f32x4 MFMA16(bf16x8 a, bf16x8 b, f32x4 c){
  return __builtin_amdgcn_mfma_f32_16x16x32_bf16(a, b, c, 0,0,0);
}

// ---------------- fused prep, heavy-first: gates (0-1023) | wtrans (1024-4095) | cvt (4096-8191) ----------------
__global__ __launch_bounds__(256)
void prep_all_kernel(const float* __restrict__ x, unsigned short* __restrict__ x_bf,
                     const float* __restrict__ Wqk, unsigned short* __restrict__ WqkT,
                     const float* __restrict__ Wproj, unsigned short* __restrict__ WprojT,
                     const float* __restrict__ Wg, const float* __restrict__ bg,
                     float* __restrict__ gates){
  __shared__ float tile[32][33];
  const int tid = threadIdx.x;
  int blk = blockIdx.x;
  if (blk < 1024){
    // ---- gates (heaviest blocks first) ----
    const int lane = tid & 63;
    const int row  = blk*4 + (tid>>6);
    const float* xr = x + (size_t)row*CEMB;
    float acc[NH];
    #pragma unroll
    for (int h=0;h<NH;h++) acc[h]=0.f;
    for (int i=0;i<CEMB/64;i++){
      float xv = xr[i*64 + lane];
      const float4* wg = reinterpret_cast<const float4*>(Wg + (size_t)(i*64+lane)*NH);
      float4 a=wg[0], b=wg[1], c=wg[2], d=wg[3];
      acc[0]+=xv*a.x; acc[1]+=xv*a.y; acc[2]+=xv*a.z; acc[3]+=xv*a.w;
      acc[4]+=xv*b.x; acc[5]+=xv*b.y; acc[6]+=xv*b.z; acc[7]+=xv*b.w;
      acc[8]+=xv*c.x; acc[9]+=xv*c.y; acc[10]+=xv*c.z; acc[11]+=xv*c.w;
      acc[12]+=xv*d.x; acc[13]+=xv*d.y; acc[14]+=xv*d.z; acc[15]+=xv*d.w;
    }
    #pragma unroll
    for (int h=0;h<NH;h++){
      #pragma unroll
      for (int m=32;m;m>>=1) acc[h] += __shfl_xor(acc[h], m, 64);
    }
    float mx = -1e30f;
    #pragma unroll
    for (int h=0;h<NH;h++){ acc[h] += bg[h]; mx = fmaxf(mx, acc[h]); }
    float s = 0.f;
    #pragma unroll
    for (int h=0;h<NH;h++){ acc[h] = __expf(acc[h]-mx); s += acc[h]; }
    float g = 0.f;
    #pragma unroll
    for (int h=0;h<NH;h++) g = (lane==h) ? acc[h]/s : g;
    if (lane < NH) gates[(size_t)row*NH + lane] = g;
  } else if (blk < 4096){
    // ---- weight transposes ----
    blk -= 1024;
    const float* W; unsigned short* Wt; int R, C, bx, by;
    if (blk < 2048){ W = Wqk;   Wt = WqkT;   R = 1024; C = 2048; bx = blk & 63; by = blk >> 6; }
    else { blk -= 2048; W = Wproj; Wt = WprojT; R = 1024; C = 1024; bx = blk & 31; by = blk >> 5; }
    const int c0 = bx*32, r0 = by*32;
    const int tx = tid & 31, ty = tid >> 5;   // (32,8)
    #pragma unroll
    for (int i=0;i<32;i+=8) tile[ty+i][tx] = W[(size_t)(r0+ty+i)*C + c0 + tx];
    __syncthreads();
    #pragma unroll
    for (int i=0;i<32;i+=8) Wt[(size_t)(c0+ty+i)*R + r0 + tx] = f2bf(tile[tx][ty+i]);
  } else {
    // ---- cvt x -> bf16 ----
    int i = ((blk-4096)*256 + tid)*4;
    float4 v = *reinterpret_cast<const float4*>(x + i);
    ushort4 o; o.x=f2bf(v.x); o.y=f2bf(v.y); o.z=f2bf(v.z); o.w=f2bf(v.w);
    *reinterpret_cast<ushort4*>(x_bf + i) = o;
  }
}

// ---------------- bf16 MFMA GEMM, depth-2 counted-vmcnt pipeline ----------------
// NW = waves/block. NW=8 (gemm1): 128x128 tile, wave=32x64, 16 waves/CU (4/SIMD).
// NW=4, BM=64 (gemm2): wave=64x32, 3 blocks/CU.
// PACK: k-half blocks (bn>=8) emit Kpack/Vpack fragments from an LDS-staged tile.
template<bool OUT_BF16, int BM, bool PACK, int NW>
__global__ __launch_bounds__(NW*64)
void gemm_bt_kernel(const unsigned short* __restrict__ A, const unsigned short* __restrict__ Bt,
                    const float* __restrict__ bias, void* __restrict__ Cptr,
                    int M, int N, int K,
                    unsigned short* __restrict__ Kpack, unsigned short* __restrict__ Vpack){
  constexpr int WRN   = (NW==8) ? 4 : (BM==128 ? 2 : 1);
  constexpr int WCN   = NW/WRN;
  constexpr int WROWS = BM/WRN;
  constexpr int WCW   = 128/WCN;
  constexpr int MFRAG = WROWS/16;
  constexpr int NFRAG = WCW/16;
  constexpr int AISS  = BM/(NW*8);               // A stage issues per thread
  constexpr int BISS  = 128/(NW*8);              // B stage issues per thread
  constexpr int LDSN  = BM*64*2 + 128*64*2;
  __shared__ __align__(16) unsigned short smem[LDSN];
  unsigned short* lA0 = smem;
  unsigned short* lA1 = smem + BM*64;
  unsigned short* lB0 = smem + BM*64*2;
  unsigned short* lB1 = smem + BM*64*2 + 128*64;
  const int tid = threadIdx.x;
  const int wid = tid>>6, lane = tid&63;
  const int nbm = M/BM;
  const int bid = blockIdx.x;
  const int bm = bid % nbm, bn = bid / nbm;
  const int wr = (WRN==1) ? 0 : (wid/WCN);
  const int wc = (WCN==1) ? 0 : (wid%WCN);
  f32x4 acc[MFRAG][NFRAG] = {};

  const unsigned short* gA = A + (size_t)bm*BM*K;
  const unsigned short* gB = Bt + (size_t)bn*128*K;
  const int srow = lane>>3;
  const int schunk = lane&7;

#define GSTAGE(LA, LB, KK) do { \
  _Pragma("unroll") \
  for (int i_=0;i_<AISS;i_++){ \
    int rowi_ = (wid*AISS+i_)*8 + srow; \
    int cc_ = schunk ^ (rowi_ & 7); \
    __builtin_amdgcn_global_load_lds((const __attribute__((address_space(1))) void*)(gA + (size_t)rowi_*K + (KK) + cc_*8), \
        (__attribute__((address_space(3))) void*)&LA[(wid*AISS+i_)*512], 16, 0, 0); \
  } \
  _Pragma("unroll") \
  for (int i_=0;i_<BISS;i_++){ \
    int rowi_ = (wid*BISS+i_)*8 + srow; \
    int cc_ = schunk ^ (rowi_ & 7); \
    __builtin_amdgcn_global_load_lds((const __attribute__((address_space(1))) void*)(gB + (size_t)rowi_*K + (KK) + cc_*8), \
        (__attribute__((address_space(3))) void*)&LB[(wid*BISS+i_)*512], 16, 0, 0); \
  } \
} while(0)

#define GCOMPUTE(LA, LB) do { \
  _Pragma("unroll") \
  for (int ks_=0; ks_<2; ks_++){ \
    bf16x8 af_[MFRAG], bf_[NFRAG]; \
    _Pragma("unroll") \
    for (int m_=0;m_<MFRAG;m_++){ \
      int r_ = wr*WROWS + m_*16 + (lane&15); \
      int p_ = (ks_*4 + (lane>>4)) ^ (r_&7); \
      af_[m_] = *reinterpret_cast<const bf16x8*>(&LA[r_*64 + p_*8]); \
    } \
    _Pragma("unroll") \
    for (int n_=0;n_<NFRAG;n_++){ \
      int r_ = wc*WCW + n_*16 + (lane&15); \
      int p_ = (ks_*4 + (lane>>4)) ^ (r_&7); \
      bf_[n_] = *reinterpret_cast<const bf16x8*>(&LB[r_*64 + p_*8]); \
    } \
    _Pragma("unroll") \
    for (int m_=0;m_<MFRAG;m_++) \
      _Pragma("unroll") \
      for (int n_=0;n_<NFRAG;n_++) \
        acc[m_][n_] = __builtin_amdgcn_mfma_f32_16x16x32_bf16(af_[m_], bf_[n_], acc[m_][n_], 0,0,0); \
  } \
} while(0)

#define WAITL do { \
  if      constexpr (AISS+BISS==4) asm volatile("s_waitcnt vmcnt(4)" ::: "memory"); \
  else if constexpr (AISS+BISS==6) asm volatile("s_waitcnt vmcnt(6)" ::: "memory"); \
  else                             asm volatile("s_waitcnt vmcnt(8)" ::: "memory"); \
  __builtin_amdgcn_s_barrier(); \
  __builtin_amdgcn_sched_barrier(0); \
} while(0)

  GSTAGE(lA0, lB0, 0);
  GSTAGE(lA1, lB1, 64);
  for (int k0=0; k0<K-128; k0+=128){
    WAITL;
    GCOMPUTE(lA0, lB0);
    __builtin_amdgcn_s_barrier();
    __builtin_amdgcn_sched_barrier(0);
    GSTAGE(lA0, lB0, k0+128);
    WAITL;
    GCOMPUTE(lA1, lB1);
    __builtin_amdgcn_s_barrier();
    __builtin_amdgcn_sched_barrier(0);
    GSTAGE(lA1, lB1, k0+192);
  }
  WAITL;
  GCOMPUTE(lA0, lB0);
  asm volatile("s_waitcnt vmcnt(0)" ::: "memory");
  __builtin_amdgcn_s_barrier();
  __builtin_amdgcn_sched_barrier(0);
  GCOMPUTE(lA1, lB1);
#undef GSTAGE
#undef GCOMPUTE
#undef WAITL

  const int rq = lane>>4;
  const int cl = lane&15;

  if constexpr (PACK){
    if (bn >= 8){
      // ---- pack epilogue: stage tile (stride 136), emit Kpack/Vpack frags ----
      __syncthreads();
      #pragma unroll
      for (int n=0;n<NFRAG;n++){
        const int c_l = wc*WCW + n*16 + cl;
        const float bv = bias[bn*128 + c_l];
        #pragma unroll
        for (int m=0;m<MFRAG;m++){
          const int r_l = wr*WROWS + m*16 + rq*4;
          #pragma unroll
          for (int r=0;r<4;r++)
            smem[(r_l+r)*136 + c_l] = f2bf(acc[m][n][r] + bv);
        }
      }
      __syncthreads();
      const int b = bm>>3;
      const int ktg0 = (bm&7)*4;
      const int g = lane>>4, li = lane&15;
      const int kt_l = wid>>1;          // 0..3: 32-row kt tile
      const int hh   = wid&1;           // head half
      const int bh = b*NH + (bn-8)*2 + hh;
      const size_t fb = ((size_t)bh*32 + ktg0 + kt_l)*4;
      #pragma unroll
      for (int f=0; f<4; f++){
        // Kpack[bh][kt][f][lane][j] = K[kt*32+(f>>1)*16+li][(f&1)*32+g*8+j]
        uint4 kv = *reinterpret_cast<const uint4*>(
            &smem[(kt_l*32 + ((f>>1)<<4) + li)*136 + hh*64 + (f&1)*32 + g*8]);
        *reinterpret_cast<uint4*>(Kpack + ((fb + f)*64 + lane)*8) = kv;
        // Vpack[bh][kt][d4][lane][j] = K[kt*32+g*8+j][d4*16+li]   (d4 = f)
        unsigned short vv[8];
        #pragma unroll
        for (int j=0;j<8;j++) vv[j] = smem[(kt_l*32 + g*8 + j)*136 + hh*64 + f*16 + li];
        *reinterpret_cast<uint4*>(Vpack + ((fb + f)*64 + lane)*8) = *reinterpret_cast<const uint4*>(vv);
      }
      return;
    }
  }

  #pragma unroll
  for (int n=0;n<NFRAG;n++){
    int col = bn*128 + wc*WCW + n*16 + cl;
    float bv = bias[col];
    #pragma unroll
    for (int m=0;m<MFRAG;m++){
      int row = bm*BM + wr*WROWS + m*16 + rq*4;
      #pragma unroll
      for (int r=0;r<4;r++){
        float v = acc[m][n][r] + bv;
        if (OUT_BF16) ((unsigned short*)Cptr)[(size_t)(row+r)*N + col] = f2bf(v);
        else          ((float*)Cptr)[(size_t)(row+r)*N + col] = v;
      }
    }
  }
}

// ---------------- MFMA attention, no-max softmax, packed frags, NO split-K ----------------
__global__ __launch_bounds__(256)
void attn_mfma_kernel(const unsigned short* __restrict__ qk,
                      const unsigned short* __restrict__ Kpack,
                      const unsigned short* __restrict__ Vpack,
                      const float* __restrict__ gates, unsigned short* __restrict__ gated){
  __shared__ unsigned short lP[4][16*40];
  const int tid = threadIdx.x;
  const int wid = tid>>6, lane = tid&63;
  const int g = lane>>4, li = lane&15;

  const int V = wid*1024 + blockIdx.x;   // [0,4096)
  const int h = V>>8;
  const int rr = V&255;
  const int b = rr>>6, qw16 = rr&63;

  int w = 1024 >> h; if (w < 4) w = 4;
  const int qw0 = qw16*16;
  const int bh = b*NH + h;

  int mylo = qw0 - w + 1; if (mylo < 0) mylo = 0;
  const int kt_start = mylo >> 5;
  const int kt_end = (qw0 + 15) >> 5;

  const unsigned short* qbase = qk + ((size_t)(b*T_SEQ + qw0 + li)*2048 + h*64 + g*8);
  const bf16x8 aq0 = *reinterpret_cast<const bf16x8*>(qbase);
  const bf16x8 aq1 = *reinterpret_cast<const bf16x8*>(qbase + 32);

  f32x4 oacc[4] = {};
  float lsum[4] = {0.f,0.f,0.f,0.f};

  const unsigned short* kp = Kpack + (size_t)bh*32*4*512;
  const unsigned short* vp = Vpack + (size_t)bh*32*4*512;
  const int loff = lane*8;

  bf16x8 kf[4], kn[4], bv[4];
  #pragma unroll
  for (int f=0; f<4; f++)
    kf[f] = *reinterpret_cast<const bf16x8*>(kp + (kt_start*4 + f)*512 + loff);

  for (int kt = kt_start; kt <= kt_end; ++kt){
    #pragma unroll
    for (int d4=0; d4<4; d4++)
      bv[d4] = *reinterpret_cast<const bf16x8*>(vp + (kt*4 + d4)*512 + loff);
    {
      const int ktn = (kt < kt_end) ? kt+1 : kt_end;
      #pragma unroll
      for (int f=0; f<4; f++)
        kn[f] = *reinterpret_cast<const bf16x8*>(kp + (ktn*4 + f)*512 + loff);
    }

    f32x4 s0 = {}, s1 = {};
    s0 = MFMA16(aq0, kf[0], s0);
    s0 = MFMA16(aq1, kf[1], s0);
    s1 = MFMA16(aq0, kf[2], s1);
    s1 = MFMA16(aq1, kf[3], s1);

    const int k0 = kt*32;
    #pragma unroll
    for (int r=0;r<4;r++){
      const int t = qw0 + g*4 + r;
      const int ka = k0 + li;
      const int kb2 = ka + 16;
      const bool v0 = (ka <= t) && (ka > t - w);
      const bool v1 = (kb2 <= t) && (kb2 > t - w);
      const float p0 = v0 ? __expf(s0[r]*0.125f) : 0.f;
      const float p1 = v1 ? __expf(s1[r]*0.125f) : 0.f;
      lsum[r] += p0 + p1;
      const int q = g*4 + r;
      lP[wid][q*40 + li]      = f2bf(p0);
      lP[wid][q*40 + 16 + li] = f2bf(p1);
    }
    const bf16x8 pa = *reinterpret_cast<const bf16x8*>(&lP[wid][li*40 + g*8]);
    #pragma unroll
    for (int d4=0; d4<4; d4++)
      oacc[d4] = MFMA16(pa, bv[d4], oacc[d4]);
    #pragma unroll
    for (int i=0;i<4;i++) kf[i] = kn[i];
  }

  #pragma unroll
  for (int msk=1; msk<16; msk<<=1){
    #pragma unroll
    for (int r=0;r<4;r++) lsum[r] += __shfl_xor(lsum[r], msk, 64);
  }

  #pragma unroll
  for (int r=0;r<4;r++){
    const int t = qw0 + g*4 + r;
    const float gv = gates[(size_t)(b*T_SEQ + t)*NH + h];
    const float inv = gv / lsum[r];
    unsigned short* orow = gated + (size_t)(b*T_SEQ + t)*CEMB + h*64 + li;
    orow[0]  = f2bf(oacc[0][r]*inv);
    orow[16] = f2bf(oacc[1][r]*inv);
    orow[32] = f2bf(oacc[2][r]*inv);
    orow[48] = f2bf(oacc[3][r]*inv);
  }
}

extern "C" void kernel_launch(void* const* d_in, const int* in_sizes, int n_in,
                              void* d_out, int out_size, void* d_ws, size_t ws_size,
                              hipStream_t stream){
  const float* x     = (const float*)d_in[0];
  const float* Wqk   = (const float*)d_in[1];
  const float* bqk   = (const float*)d_in[2];
  const float* Wgate = (const float*)d_in[3];
  const float* bgate = (const float*)d_in[4];
  const float* Wproj = (const float*)d_in[5];
  const float* bproj = (const float*)d_in[6];
  float* out = (float*)d_out;

  // workspace layout (~56MB of the 256MB ws)
  unsigned short* x_bf   = (unsigned short*)d_ws;                 // 8MB
  unsigned short* WqkT   = x_bf   + (size_t)4096*1024;            // 4MB
  unsigned short* WprojT = WqkT   + (size_t)2048*1024;            // 2MB
  unsigned short* qkb    = WprojT + (size_t)1024*1024;            // 16MB (k-half unused)
  unsigned short* gated  = qkb    + (size_t)4096*2048;            // 8MB
  float*          gates  = (float*)(gated + (size_t)4096*1024);   // 256KB
  unsigned short* Kpack  = (unsigned short*)((char*)d_ws + (size_t)40*1024*1024);  // 8MB
  unsigned short* Vpack  = Kpack + (size_t)64*32*4*512;                            // 8MB

  prep_all_kernel<<<8192, 256, 0, stream>>>(x, x_bf, Wqk, WqkT, Wproj, WprojT, Wgate, bgate, gates);

  gemm_bt_kernel<true, 128, true, 8><<<512, 512, 0, stream>>>(x_bf, WqkT, bqk, qkb,
                                                              4096, 2048, 1024, Kpack, Vpack);
  attn_mfma_kernel<<<1024, 256, 0, stream>>>(qkb, Kpack, Vpack, gates, gated);
  gemm_bt_kernel<false, 64, false, 4><<<512, 256, 0, stream>>>(gated, WprojT, bproj, out,
                                                               4096, 1024, 1024, nullptr, nullptr);
}

// Round 16
// 89.032 us; speedup vs baseline: 1.2790x; 1.0020x over previous
//
#include <hip/hip_runtime.h>

typedef __attribute__((ext_vector_type(8))) short bf16x8;
typedef __attribute__((ext_vector_type(4))) float f32x4;

#define T_SEQ 1024
#define NH 16
#define CEMB 1024

__device__ __forceinline__ float asf(unsigned int u){ union{unsigned int i;float f;}x; x.i=u; return x.f; }
__device__ __forceinline__ float bf2f(unsigned short u){ return asf(((unsigned int)u)<<16); }
__device__ __forceinline__ unsigned short f2bf(float f){
  union{float f;unsigned int i;}x; x.f=f;
  unsigned int r = x.i + 0x7FFFu + ((x.i>>16)&1u);
  return (unsigned short)(r>>16);
}
__device__ __forceinline__ f32x4 MFMA16(bf16x8 a, bf16x8 b, f32x4 c){
  return __builtin_amdgcn_mfma_f32_16x16x32_bf16(a, b, c, 0,0,0);
}

// ---------------- fused prep, heavy-first: gates (0-1023) | wtrans (1024-4095) | cvt (4096-8191) ----------------
__global__ __launch_bounds__(256)
void prep_all_kernel(const float* __restrict__ x, unsigned short* __restrict__ x_bf,
                     const float* __restrict__ Wqk, unsigned short* __restrict__ WqkT,
                     const float* __restrict__ Wproj, unsigned short* __restrict__ WprojT,
                     const float* __restrict__ Wg, const float* __restrict__ bg,
                     float* __restrict__ gates){
  __shared__ float tile[32][33];
  const int tid = threadIdx.x;
  int blk = blockIdx.x;
  if (blk < 1024){
    // ---- gates (heaviest blocks first) ----
    const int lane = tid & 63;
    const int row  = blk*4 + (tid>>6);
    const float* xr = x + (size_t)row*CEMB;
    float acc[NH];
    #pragma unroll
    for (int h=0;h<NH;h++) acc[h]=0.f;
    for (int i=0;i<CEMB/64;i++){
      float xv = xr[i*64 + lane];
      const float4* wg = reinterpret_cast<const float4*>(Wg + (size_t)(i*64+lane)*NH);
      float4 a=wg[0], b=wg[1], c=wg[2], d=wg[3];
      acc[0]+=xv*a.x; acc[1]+=xv*a.y; acc[2]+=xv*a.z; acc[3]+=xv*a.w;
      acc[4]+=xv*b.x; acc[5]+=xv*b.y; acc[6]+=xv*b.z; acc[7]+=xv*b.w;
      acc[8]+=xv*c.x; acc[9]+=xv*c.y; acc[10]+=xv*c.z; acc[11]+=xv*c.w;
      acc[12]+=xv*d.x; acc[13]+=xv*d.y; acc[14]+=xv*d.z; acc[15]+=xv*d.w;
    }
    #pragma unroll
    for (int h=0;h<NH;h++){
      #pragma unroll
      for (int m=32;m;m>>=1) acc[h] += __shfl_xor(acc[h], m, 64);
    }
    float mx = -1e30f;
    #pragma unroll
    for (int h=0;h<NH;h++){ acc[h] += bg[h]; mx = fmaxf(mx, acc[h]); }
    float s = 0.f;
    #pragma unroll
    for (int h=0;h<NH;h++){ acc[h] = __expf(acc[h]-mx); s += acc[h]; }
    float g = 0.f;
    #pragma unroll
    for (int h=0;h<NH;h++) g = (lane==h) ? acc[h]/s : g;
    if (lane < NH) gates[(size_t)row*NH + lane] = g;
  } else if (blk < 4096){
    // ---- weight transposes ----
    blk -= 1024;
    const float* W; unsigned short* Wt; int R, C, bx, by;
    if (blk < 2048){ W = Wqk;   Wt = WqkT;   R = 1024; C = 2048; bx = blk & 63; by = blk >> 6; }
    else { blk -= 2048; W = Wproj; Wt = WprojT; R = 1024; C = 1024; bx = blk & 31; by = blk >> 5; }
    const int c0 = bx*32, r0 = by*32;
    const int tx = tid & 31, ty = tid >> 5;   // (32,8)
    #pragma unroll
    for (int i=0;i<32;i+=8) tile[ty+i][tx] = W[(size_t)(r0+ty+i)*C + c0 + tx];
    __syncthreads();
    #pragma unroll
    for (int i=0;i<32;i+=8) Wt[(size_t)(c0+ty+i)*R + r0 + tx] = f2bf(tile[tx][ty+i]);
  } else {
    // ---- cvt x -> bf16 ----
    int i = ((blk-4096)*256 + tid)*4;
    float4 v = *reinterpret_cast<const float4*>(x + i);
    ushort4 o; o.x=f2bf(v.x); o.y=f2bf(v.y); o.z=f2bf(v.z); o.w=f2bf(v.w);
    *reinterpret_cast<ushort4*>(x_bf + i) = o;
  }
}

// ---------------- bf16 MFMA GEMM, depth-2 counted-vmcnt pipeline ----------------
// NW=8 everywhere: gemm1 128x128 tile (wave 32x64, 2 blocks/CU = 16 waves/CU);
// gemm2 BM=64 (wave 16x64... wave 16x64? WRN=4,WCN=2 -> wave 16x64; 3 blocks/CU = 24 waves/CU).
// PACK: k-half blocks (bn>=8) emit Kpack/Vpack fragments from an LDS-staged tile.
template<bool OUT_BF16, int BM, bool PACK, int NW>
__global__ __launch_bounds__(NW*64)
void gemm_bt_kernel(const unsigned short* __restrict__ A, const unsigned short* __restrict__ Bt,
                    const float* __restrict__ bias, void* __restrict__ Cptr,
                    int M, int N, int K,
                    unsigned short* __restrict__ Kpack, unsigned short* __restrict__ Vpack){
  constexpr int WRN   = (NW==8) ? 4 : (BM==128 ? 2 : 1);
  constexpr int WCN   = NW/WRN;
  constexpr int WROWS = BM/WRN;
  constexpr int WCW   = 128/WCN;
  constexpr int MFRAG = WROWS/16;
  constexpr int NFRAG = WCW/16;
  constexpr int AISS  = BM/(NW*8);               // A stage issues per thread
  constexpr int BISS  = 128/(NW*8);              // B stage issues per thread
  constexpr int LDSN  = BM*64*2 + 128*64*2;
  __shared__ __align__(16) unsigned short smem[LDSN];
  unsigned short* lA0 = smem;
  unsigned short* lA1 = smem + BM*64;
  unsigned short* lB0 = smem + BM*64*2;
  unsigned short* lB1 = smem + BM*64*2 + 128*64;
  const int tid = threadIdx.x;
  const int wid = tid>>6, lane = tid&63;
  const int nbm = M/BM;
  const int bid = blockIdx.x;
  const int bm = bid % nbm, bn = bid / nbm;
  const int wr = (WRN==1) ? 0 : (wid/WCN);
  const int wc = (WCN==1) ? 0 : (wid%WCN);
  f32x4 acc[MFRAG][NFRAG] = {};

  const unsigned short* gA = A + (size_t)bm*BM*K;
  const unsigned short* gB = Bt + (size_t)bn*128*K;
  const int srow = lane>>3;
  const int schunk = lane&7;

#define GSTAGE(LA, LB, KK) do { \
  _Pragma("unroll") \
  for (int i_=0;i_<AISS;i_++){ \
    int rowi_ = (wid*AISS+i_)*8 + srow; \
    int cc_ = schunk ^ (rowi_ & 7); \
    __builtin_amdgcn_global_load_lds((const __attribute__((address_space(1))) void*)(gA + (size_t)rowi_*K + (KK) + cc_*8), \
        (__attribute__((address_space(3))) void*)&LA[(wid*AISS+i_)*512], 16, 0, 0); \
  } \
  _Pragma("unroll") \
  for (int i_=0;i_<BISS;i_++){ \
    int rowi_ = (wid*BISS+i_)*8 + srow; \
    int cc_ = schunk ^ (rowi_ & 7); \
    __builtin_amdgcn_global_load_lds((const __attribute__((address_space(1))) void*)(gB + (size_t)rowi_*K + (KK) + cc_*8), \
        (__attribute__((address_space(3))) void*)&LB[(wid*BISS+i_)*512], 16, 0, 0); \
  } \
} while(0)

#define GCOMPUTE(LA, LB) do { \
  _Pragma("unroll") \
  for (int ks_=0; ks_<2; ks_++){ \
    bf16x8 af_[MFRAG], bf_[NFRAG]; \
    _Pragma("unroll") \
    for (int m_=0;m_<MFRAG;m_++){ \
      int r_ = wr*WROWS + m_*16 + (lane&15); \
      int p_ = (ks_*4 + (lane>>4)) ^ (r_&7); \
      af_[m_] = *reinterpret_cast<const bf16x8*>(&LA[r_*64 + p_*8]); \
    } \
    _Pragma("unroll") \
    for (int n_=0;n_<NFRAG;n_++){ \
      int r_ = wc*WCW + n_*16 + (lane&15); \
      int p_ = (ks_*4 + (lane>>4)) ^ (r_&7); \
      bf_[n_] = *reinterpret_cast<const bf16x8*>(&LB[r_*64 + p_*8]); \
    } \
    _Pragma("unroll") \
    for (int m_=0;m_<MFRAG;m_++) \
      _Pragma("unroll") \
      for (int n_=0;n_<NFRAG;n_++) \
        acc[m_][n_] = __builtin_amdgcn_mfma_f32_16x16x32_bf16(af_[m_], bf_[n_], acc[m_][n_], 0,0,0); \
  } \
} while(0)

#define WAITL do { \
  if      constexpr (AISS+BISS==3) asm volatile("s_waitcnt vmcnt(3)" ::: "memory"); \
  else if constexpr (AISS+BISS==4) asm volatile("s_waitcnt vmcnt(4)" ::: "memory"); \
  else if constexpr (AISS+BISS==6) asm volatile("s_waitcnt vmcnt(6)" ::: "memory"); \
  else                             asm volatile("s_waitcnt vmcnt(8)" ::: "memory"); \
  __builtin_amdgcn_s_barrier(); \
  __builtin_amdgcn_sched_barrier(0); \
} while(0)

  GSTAGE(lA0, lB0, 0);
  GSTAGE(lA1, lB1, 64);
  for (int k0=0; k0<K-128; k0+=128){
    WAITL;
    GCOMPUTE(lA0, lB0);
    __builtin_amdgcn_s_barrier();
    __builtin_amdgcn_sched_barrier(0);
    GSTAGE(lA0, lB0, k0+128);
    WAITL;
    GCOMPUTE(lA1, lB1);
    __builtin_amdgcn_s_barrier();
    __builtin_amdgcn_sched_barrier(0);
    GSTAGE(lA1, lB1, k0+192);
  }
  WAITL;
  GCOMPUTE(lA0, lB0);
  asm volatile("s_waitcnt vmcnt(0)" ::: "memory");
  __builtin_amdgcn_s_barrier();
  __builtin_amdgcn_sched_barrier(0);
  GCOMPUTE(lA1, lB1);
#undef GSTAGE
#undef GCOMPUTE
#undef WAITL

  const int rq = lane>>4;
  const int cl = lane&15;

  if constexpr (PACK){
    if (bn >= 8){
      // ---- pack epilogue: stage tile (stride 136), emit Kpack/Vpack frags ----
      __syncthreads();
      #pragma unroll
      for (int n=0;n<NFRAG;n++){
        const int c_l = wc*WCW + n*16 + cl;
        const float bv = bias[bn*128 + c_l];
        #pragma unroll
        for (int m=0;m<MFRAG;m++){
          const int r_l = wr*WROWS + m*16 + rq*4;
          #pragma unroll
          for (int r=0;r<4;r++)
            smem[(r_l+r)*136 + c_l] = f2bf(acc[m][n][r] + bv);
        }
      }
      __syncthreads();
      const int b = bm>>3;
      const int ktg0 = (bm&7)*4;
      const int g = lane>>4, li = lane&15;
      const int kt_l = wid>>1;          // 0..3: 32-row kt tile
      const int hh   = wid&1;           // head half
      const int bh = b*NH + (bn-8)*2 + hh;
      const size_t fb = ((size_t)bh*32 + ktg0 + kt_l)*4;
      #pragma unroll
      for (int f=0; f<4; f++){
        // Kpack[bh][kt][f][lane][j] = K[kt*32+(f>>1)*16+li][(f&1)*32+g*8+j]
        uint4 kv = *reinterpret_cast<const uint4*>(
            &smem[(kt_l*32 + ((f>>1)<<4) + li)*136 + hh*64 + (f&1)*32 + g*8]);
        *reinterpret_cast<uint4*>(Kpack + ((fb + f)*64 + lane)*8) = kv;
        // Vpack[bh][kt][d4][lane][j] = K[kt*32+g*8+j][d4*16+li]   (d4 = f)
        unsigned short vv[8];
        #pragma unroll
        for (int j=0;j<8;j++) vv[j] = smem[(kt_l*32 + g*8 + j)*136 + hh*64 + f*16 + li];
        *reinterpret_cast<uint4*>(Vpack + ((fb + f)*64 + lane)*8) = *reinterpret_cast<const uint4*>(vv);
      }
      return;
    }
  }

  #pragma unroll
  for (int n=0;n<NFRAG;n++){
    int col = bn*128 + wc*WCW + n*16 + cl;
    float bv = bias[col];
    #pragma unroll
    for (int m=0;m<MFRAG;m++){
      int row = bm*BM + wr*WROWS + m*16 + rq*4;
      #pragma unroll
      for (int r=0;r<4;r++){
        float v = acc[m][n][r] + bv;
        if (OUT_BF16) ((unsigned short*)Cptr)[(size_t)(row+r)*N + col] = f2bf(v);
        else          ((float*)Cptr)[(size_t)(row+r)*N + col] = v;
      }
    }
  }
}

// ---------------- MFMA attention, no-max softmax, packed frags, NO split-K ----------------
__global__ __launch_bounds__(256)
void attn_mfma_kernel(const unsigned short* __restrict__ qk,
                      const unsigned short* __restrict__ Kpack,
                      const unsigned short* __restrict__ Vpack,
                      const float* __restrict__ gates, unsigned short* __restrict__ gated){
  __shared__ unsigned short lP[4][16*40];
  const int tid = threadIdx.x;
  const int wid = tid>>6, lane = tid&63;
  const int g = lane>>4, li = lane&15;

  const int V = wid*1024 + blockIdx.x;   // [0,4096)
  const int h = V>>8;
  const int rr = V&255;
  const int b = rr>>6, qw16 = rr&63;

  int w = 1024 >> h; if (w < 4) w = 4;
  const int qw0 = qw16*16;
  const int bh = b*NH + h;

  int mylo = qw0 - w + 1; if (mylo < 0) mylo = 0;
  const int kt_start = mylo >> 5;
  const int kt_end = (qw0 + 15) >> 5;

  const unsigned short* qbase = qk + ((size_t)(b*T_SEQ + qw0 + li)*2048 + h*64 + g*8);
  const bf16x8 aq0 = *reinterpret_cast<const bf16x8*>(qbase);
  const bf16x8 aq1 = *reinterpret_cast<const bf16x8*>(qbase + 32);

  f32x4 oacc[4] = {};
  float lsum[4] = {0.f,0.f,0.f,0.f};

  const unsigned short* kp = Kpack + (size_t)bh*32*4*512;
  const unsigned short* vp = Vpack + (size_t)bh*32*4*512;
  const int loff = lane*8;

  bf16x8 kf[4], kn[4], bv[4];
  #pragma unroll
  for (int f=0; f<4; f++)
    kf[f] = *reinterpret_cast<const bf16x8*>(kp + (kt_start*4 + f)*512 + loff);

  for (int kt = kt_start; kt <= kt_end; ++kt){
    #pragma unroll
    for (int d4=0; d4<4; d4++)
      bv[d4] = *reinterpret_cast<const bf16x8*>(vp + (kt*4 + d4)*512 + loff);
    {
      const int ktn = (kt < kt_end) ? kt+1 : kt_end;
      #pragma unroll
      for (int f=0; f<4; f++)
        kn[f] = *reinterpret_cast<const bf16x8*>(kp + (ktn*4 + f)*512 + loff);
    }

    f32x4 s0 = {}, s1 = {};
    s0 = MFMA16(aq0, kf[0], s0);
    s0 = MFMA16(aq1, kf[1], s0);
    s1 = MFMA16(aq0, kf[2], s1);
    s1 = MFMA16(aq1, kf[3], s1);

    const int k0 = kt*32;
    #pragma unroll
    for (int r=0;r<4;r++){
      const int t = qw0 + g*4 + r;
      const int ka = k0 + li;
      const int kb2 = ka + 16;
      const bool v0 = (ka <= t) && (ka > t - w);
      const bool v1 = (kb2 <= t) && (kb2 > t - w);
      const float p0 = v0 ? __expf(s0[r]*0.125f) : 0.f;
      const float p1 = v1 ? __expf(s1[r]*0.125f) : 0.f;
      lsum[r] += p0 + p1;
      const int q = g*4 + r;
      lP[wid][q*40 + li]      = f2bf(p0);
      lP[wid][q*40 + 16 + li] = f2bf(p1);
    }
    const bf16x8 pa = *reinterpret_cast<const bf16x8*>(&lP[wid][li*40 + g*8]);
    #pragma unroll
    for (int d4=0; d4<4; d4++)
      oacc[d4] = MFMA16(pa, bv[d4], oacc[d4]);
    #pragma unroll
    for (int i=0;i<4;i++) kf[i] = kn[i];
  }

  #pragma unroll
  for (int msk=1; msk<16; msk<<=1){
    #pragma unroll
    for (int r=0;r<4;r++) lsum[r] += __shfl_xor(lsum[r], msk, 64);
  }

  #pragma unroll
  for (int r=0;r<4;r++){
    const int t = qw0 + g*4 + r;
    const float gv = gates[(size_t)(b*T_SEQ + t)*NH + h];
    const float inv = gv / lsum[r];
    unsigned short* orow = gated + (size_t)(b*T_SEQ + t)*CEMB + h*64 + li;
    orow[0]  = f2bf(oacc[0][r]*inv);
    orow[16] = f2bf(oacc[1][r]*inv);
    orow[32] = f2bf(oacc[2][r]*inv);
    orow[48] = f2bf(oacc[3][r]*inv);
  }
}

extern "C" void kernel_launch(void* const* d_in, const int* in_sizes, int n_in,
                              void* d_out, int out_size, void* d_ws, size_t ws_size,
                              hipStream_t stream){
  const float* x     = (const float*)d_in[0];
  const float* Wqk   = (const float*)d_in[1];
  const float* bqk   = (const float*)d_in[2];
  const float* Wgate = (const float*)d_in[3];
  const float* bgate = (const float*)d_in[4];
  const float* Wproj = (const float*)d_in[5];
  const float* bproj = (const float*)d_in[6];
  float* out = (float*)d_out;

  // workspace layout (~56MB of the 256MB ws)
  unsigned short* x_bf   = (unsigned short*)d_ws;                 // 8MB
  unsigned short* WqkT   = x_bf   + (size_t)4096*1024;            // 4MB
  unsigned short* WprojT = WqkT   + (size_t)2048*1024;            // 2MB
  unsigned short* qkb    = WprojT + (size_t)1024*1024;            // 16MB (k-half unused)
  unsigned short* gated  = qkb    + (size_t)4096*2048;            // 8MB
  float*          gates  = (float*)(gated + (size_t)4096*1024);   // 256KB
  unsigned short* Kpack  = (unsigned short*)((char*)d_ws + (size_t)40*1024*1024);  // 8MB
  unsigned short* Vpack  = Kpack + (size_t)64*32*4*512;                            // 8MB

  prep_all_kernel<<<8192, 256, 0, stream>>>(x, x_bf, Wqk, WqkT, Wproj, WprojT, Wgate, bgate, gates);

  gemm_bt_kernel<true, 128, true, 8><<<512, 512, 0, stream>>>(x_bf, WqkT, bqk, qkb,
                                                              4096, 2048, 1024, Kpack, Vpack);
  attn_mfma_kernel<<<1024, 256, 0, stream>>>(qkb, Kpack, Vpack, gates, gated);
  gemm_bt_kernel<false, 64, false, 8><<<512, 512, 0, stream>>>(gated, WprojT, bproj, out,
                                                               4096, 1024, 1024, nullptr, nullptr);
}